// Round 7
// baseline (41697.293 us; speedup 1.0000x reference)
//
#include <hip/hip_runtime.h>
#include <hip/hip_fp16.h>

#define HID   512
#define EMB   256
#define VOCAB 64
#define BS    64
#define SLEN  128
#define LLEN  1024
#define G4    2048
#define NB    256
#define NT    512

typedef unsigned u32x4 __attribute__((ext_vector_type(4)));

// ---------------------------------------------------------------------------
// MALL-coherent access helpers (volatile -> cache-bypass, proven R5/R6)
__device__ __forceinline__ u32x4 vldq(const unsigned* p) {
    return *reinterpret_cast<const volatile u32x4*>(p);
}
__device__ __forceinline__ float vld1(const float* p) {
    return *reinterpret_cast<const volatile float*>(p);
}
__device__ __forceinline__ void vst1(float* p, float v) {
    *reinterpret_cast<volatile float*>(p) = v;
}
__device__ __forceinline__ unsigned packh2(float x, float y) {
    __half2 h = __floats2half2_rn(x, y);
    return *reinterpret_cast<unsigned*>(&h);
}

// ---------------------------------------------------------------------------
struct SRed  { float red[8][10][66]; };
struct SAttn { float u_s[512]; float w_s[32]; float msh[4];
               float accs[16][34]; unsigned enc[32 * 261]; };
union SMem { SRed r; SAttn a; };

// ---------------------------------------------------------------------------
// grid barrier v4: slot-store arrival (no RMW), block-0 parallel checker,
// 8 padded release words. All relaxed; visibility via write-through + the
// vmcnt(0) drain in __syncthreads (proven R4-R6 protocol).
__device__ __forceinline__ void gridbar(unsigned* bar, unsigned nb)
{
    __syncthreads();
    const int t = threadIdx.x;
    if (blockIdx.x == 0) {
        if (t == 0)
            __hip_atomic_store(bar + 0, nb, __ATOMIC_RELAXED, __HIP_MEMORY_SCOPE_AGENT);
        if (t < 256) {
            while (__hip_atomic_load(bar + t, __ATOMIC_RELAXED,
                                     __HIP_MEMORY_SCOPE_AGENT) < nb)
                __builtin_amdgcn_s_sleep(1);
        }
        __syncthreads();
        if (t < 8)
            __hip_atomic_store(bar + 256 + t * 32, nb, __ATOMIC_RELAXED,
                               __HIP_MEMORY_SCOPE_AGENT);
    } else {
        if (t == 0) {
            __hip_atomic_store(bar + blockIdx.x, nb, __ATOMIC_RELAXED,
                               __HIP_MEMORY_SCOPE_AGENT);
            unsigned* rel = bar + 256 + (blockIdx.x >> 5) * 32;
            while (__hip_atomic_load(rel, __ATOMIC_RELAXED,
                                     __HIP_MEMORY_SCOPE_AGENT) < nb)
                __builtin_amdgcn_s_sleep(1);
        }
    }
    __syncthreads();
}

// ---------------------------------------------------------------------------
// one-time kernels
__global__ __launch_bounds__(256)
void k_embed16(const int* __restrict__ y, const float* __restrict__ emb,
               __half* __restrict__ xemb16)   // [t][b][256] f16
{
    int i = blockIdx.x * 256 + threadIdx.x;
    int ts = i >> 14;
    int r  = i & 16383;
    int b  = r >> 8;
    int e  = r & 255;
    xemb16[i] = __float2half(emb[y[b * SLEN + ts] * EMB + e]);
}

__global__ __launch_bounds__(256)
void k_cast(const float* __restrict__ src, __half* __restrict__ dst, int n4)
{
    int i = blockIdx.x * 256 + threadIdx.x;
    int stride = gridDim.x * 256;
    for (; i < n4; i += stride) {
        float4 v = reinterpret_cast<const float4*>(src)[i];
        reinterpret_cast<__half2*>(dst)[2 * i]     = __floats2half2_rn(v.x, v.y);
        reinterpret_cast<__half2*>(dst)[2 * i + 1] = __floats2half2_rn(v.z, v.w);
    }
}

__global__ __launch_bounds__(256)
void k_pmat(const float* __restrict__ Whw, const float* __restrict__ Wsw,
            const float* __restrict__ Wsb, float* __restrict__ P,
            float* __restrict__ p0)
{
    const int i = blockIdx.x;
    const int t = threadIdx.x;
    float a0 = 0.f, a1 = 0.f, ap = 0.f;
    for (int h = 0; h < HID; ++h) {
        float whi = Whw[h * HID + i];
        a0 += whi * Wsw[h * HID + t];
        a1 += whi * Wsw[h * HID + t + 256];
        ap += whi * Wsb[h];
    }
    P[i * HID + t]       = a0;
    P[i * HID + t + 256] = a1;
    if (t == 0) p0[i] = ap;
}

// fold: Wp[r] = aWih_ctx[r]@Whw (r<2048); W1bp[r] = W1b[r]@Whw (r>=2048)
// bias folds: bihEff = abih + aWih_ctx@Whb ; b1eff = b1 + W1b@Whb
__global__ __launch_bounds__(256)
void k_fold(const float* __restrict__ aWih, const float* __restrict__ W1,
            const float* __restrict__ Whw, const float* __restrict__ Whb,
            const float* __restrict__ abih, const float* __restrict__ b1,
            float* __restrict__ Wp, float* __restrict__ W1bp,
            float* __restrict__ bihEff, float* __restrict__ b1eff)
{
    const int r = blockIdx.x;
    const int t = threadIdx.x;
    __shared__ float ssrc[512];
    const float* src;
    float* dst;
    if (r < G4) { src = aWih + (size_t)r * (EMB + HID) + EMB; dst = Wp + (size_t)r * HID; }
    else        { src = W1 + (size_t)(r - G4) * (2 * HID) + HID; dst = W1bp + (size_t)(r - G4) * HID; }
    ssrc[t]       = src[t];
    ssrc[t + 256] = src[t + 256];
    __syncthreads();
    float a0 = 0.f, a1 = 0.f;
    for (int h = 0; h < HID; ++h) {
        const float s = ssrc[h];
        a0 += s * Whw[h * HID + t];
        a1 += s * Whw[h * HID + t + 256];
    }
    dst[t]       = a0;
    dst[t + 256] = a1;
    if (t == 0) {
        float bb = 0.f;
        for (int h = 0; h < HID; ++h) bb += ssrc[h] * Whb[h];
        if (r < G4) bihEff[r] = abih[r] + bb;
        else        b1eff[r - G4] = b1[r - G4] + bb;
    }
}

// ---------------------------------------------------------------------------
// direct-read f16 activation scan: thread (wv,lane) reads row b=lane,
// k in [j*256 + wv*32, +32) per tile (64B, full line). Loads batched first.
template<int NTILES, int NR, bool VOL>
__device__ __forceinline__ void scanSeg(const __half* A, const float* const* w,
                                        float* acc, int wv, int lane)
{
    constexpr int K = NTILES * 256;
    const unsigned* base = reinterpret_cast<const unsigned*>(A)
                         + (size_t)lane * (K / 2) + wv * 16;
    u32x4 q[NTILES][4];
#pragma unroll
    for (int j = 0; j < NTILES; ++j)
#pragma unroll
        for (int i = 0; i < 4; ++i) {
            const unsigned* p = base + j * 128 + i * 4;
            q[j][i] = VOL ? vldq(p) : *reinterpret_cast<const u32x4*>(p);
        }
#pragma unroll
    for (int j = 0; j < NTILES; ++j) {
        const int kq = j * 256 + wv * 32;
#pragma unroll
        for (int i = 0; i < 4; ++i)
#pragma unroll
            for (int h = 0; h < 4; ++h) {
                unsigned uw = q[j][i][h];
                float2 a2 = __half22float2(*reinterpret_cast<const __half2*>(&uw));
                const int k = kq + i * 8 + h * 2;
#pragma unroll
                for (int r = 0; r < NR; ++r)
                    acc[r] += a2.x * w[r][k] + a2.y * w[r][k + 1];
            }
    }
}

// ---------------------------------------------------------------------------
// attention-input LSTM cell + fused hid(t-1) (phase A)
__device__ __forceinline__ void phaseA(SMem& sm, int i0,
    const __half* xA, const __half* chat16, const __half* h0r,
    const float* __restrict__ aWih, const float* __restrict__ Wp,
    const float* __restrict__ aWhh, const float* __restrict__ W1bp,
    const float* __restrict__ bihEff, const float* __restrict__ abhh,
    float* cp, const float* hpartPriv,
    __half* h0w, __half* hid16,
    float (&htmp)[2][64], float (&htmp2)[2][64], int wv, int lane)
{
    float acc[10] = {};
    {
        const float* wp[8];
#pragma unroll
        for (int r = 0; r < 8; ++r)
            wp[r] = aWih + (size_t)((r >> 1) * HID + i0 + (r & 1)) * (EMB + HID);
        scanSeg<1, 8, false>(xA, wp, acc, wv, lane);
    }
    {
        const float* wp[10];
#pragma unroll
        for (int r = 0; r < 8; ++r)
            wp[r] = Wp + (size_t)((r >> 1) * HID + i0 + (r & 1)) * HID;
        wp[8] = W1bp + (size_t)i0 * HID;
        wp[9] = W1bp + (size_t)(i0 + 1) * HID;
        scanSeg<2, 10, true>(chat16, wp, acc, wv, lane);
    }
    {
        const float* wp[8];
#pragma unroll
        for (int r = 0; r < 8; ++r)
            wp[r] = aWhh + (size_t)((r >> 1) * HID + i0 + (r & 1)) * HID;
        scanSeg<2, 8, true>(h0r, wp, acc, wv, lane);
    }
#pragma unroll
    for (int r = 0; r < 10; ++r) sm.r.red[wv][r][lane] = acc[r];
    __syncthreads();
    const int t = threadIdx.x;
    if (t < 128) {
        const int b = t & 63, hl = t >> 6;
        float gs[4];
#pragma unroll
        for (int g = 0; g < 4; ++g) {
            const int row = g * HID + i0 + hl;
            float s = bihEff[row] + abhh[row];
#pragma unroll
            for (int w = 0; w < 8; ++w) s += sm.r.red[w][g * 2 + hl][b];
            gs[g] = s;
        }
        const float ig = 1.f / (1.f + __expf(-gs[0]));
        const float fg = 1.f / (1.f + __expf(-gs[1]));
        const float gg = tanhf(gs[2]);
        const float og = 1.f / (1.f + __expf(-gs[3]));
        const float c2 = fg * cp[hl * 64 + b] + ig * gg;
        cp[hl * 64 + b] = c2;
        htmp[hl][b] = og * tanhf(c2);
    } else if (t < 256) {
        const int b = t & 63, hl = (t >> 6) - 2;
        float s = hpartPriv[hl * 64 + b];
#pragma unroll
        for (int w = 0; w < 8; ++w) s += sm.r.red[w][8 + hl][b];
        htmp2[hl][b] = fmaxf(s, 0.f);
    }
    __syncthreads();
    if (t < 64) {
        *reinterpret_cast<volatile unsigned*>(
            reinterpret_cast<char*>(h0w) + (size_t)t * 1024 + i0 * 2)
            = packh2(htmp[0][t], htmp[1][t]);
        *reinterpret_cast<volatile unsigned*>(
            reinterpret_cast<char*>(hid16) + (size_t)t * 1024 + i0 * 2)
            = packh2(htmp2[0][t], htmp2[1][t]);
    }
}

// plain rnn LSTM cell (phases B, C)
__device__ __forceinline__ void phaseR(SMem& sm, int i0,
    const __half* inH, const __half* recH,
    const float* __restrict__ Wih, const float* __restrict__ Whh,
    const float* __restrict__ bih, const float* __restrict__ bhh,
    float* cp, __half* hOut, float (&htmp)[2][64], int wv, int lane)
{
    float acc[8] = {};
    {
        const float* wp[8];
#pragma unroll
        for (int r = 0; r < 8; ++r)
            wp[r] = Wih + (size_t)((r >> 1) * HID + i0 + (r & 1)) * HID;
        scanSeg<2, 8, true>(inH, wp, acc, wv, lane);
    }
    {
        const float* wp[8];
#pragma unroll
        for (int r = 0; r < 8; ++r)
            wp[r] = Whh + (size_t)((r >> 1) * HID + i0 + (r & 1)) * HID;
        scanSeg<2, 8, true>(recH, wp, acc, wv, lane);
    }
#pragma unroll
    for (int r = 0; r < 8; ++r) sm.r.red[wv][r][lane] = acc[r];
    __syncthreads();
    const int t = threadIdx.x;
    if (t < 128) {
        const int b = t & 63, hl = t >> 6;
        float gs[4];
#pragma unroll
        for (int g = 0; g < 4; ++g) {
            const int row = g * HID + i0 + hl;
            float s = bih[row] + bhh[row];
#pragma unroll
            for (int w = 0; w < 8; ++w) s += sm.r.red[w][g * 2 + hl][b];
            gs[g] = s;
        }
        const float ig = 1.f / (1.f + __expf(-gs[0]));
        const float fg = 1.f / (1.f + __expf(-gs[1]));
        const float gg = tanhf(gs[2]);
        const float og = 1.f / (1.f + __expf(-gs[3]));
        const float c2 = fg * cp[hl * 64 + b] + ig * gg;
        cp[hl * 64 + b] = c2;
        htmp[hl][b] = og * tanhf(c2);
    }
    __syncthreads();
    if (t < 64)
        *reinterpret_cast<volatile unsigned*>(
            reinterpret_cast<char*>(hOut) + (size_t)t * 1024 + i0 * 2)
            = packh2(htmp[0][t], htmp[1][t]);
}

// dual GEMV: u = Pm@prev + p0 ; hpart(LDS) = W1a@prev + b1eff (phase D)
__device__ __forceinline__ void phaseD(SMem& sm, int i0,
    const __half* prevH, const float* __restrict__ Pm,
    const float* __restrict__ p0v, const float* __restrict__ W1,
    const float* __restrict__ b1eff, float* u, float* hpartPriv,
    int wv, int lane)
{
    float acc[4] = {};
    const float* wp[4];
    wp[0] = Pm + (size_t)i0 * HID;
    wp[1] = Pm + (size_t)(i0 + 1) * HID;
    wp[2] = W1 + (size_t)i0 * (2 * HID);
    wp[3] = W1 + (size_t)(i0 + 1) * (2 * HID);
    scanSeg<2, 4, true>(prevH, wp, acc, wv, lane);
#pragma unroll
    for (int r = 0; r < 4; ++r) sm.r.red[wv][r][lane] = acc[r];
    __syncthreads();
    const int t = threadIdx.x;
    if (t < 256) {
        const int b = t & 63, r = t >> 6;
        float s = 0.f;
#pragma unroll
        for (int w = 0; w < 8; ++w) s += sm.r.red[w][r][b];
        if (r < 2) vst1(u + (size_t)b * HID + i0 + r, s + p0v[i0 + r]);
        else       hpartPriv[(r - 2) * 64 + b] = s + b1eff[i0 + r - 2];
    }
}

// logits for one step-row (blocks 0..63, b = blockIdx)
__device__ __forceinline__ void logitsPhase(int b, int trow,
    const __half* hid16, const float* __restrict__ W2,
    const float* __restrict__ b2, float* __restrict__ out, float* logred)
{
    const int t = threadIdx.x;
    const int v = t >> 3, part = t & 7;
    const unsigned* hp = reinterpret_cast<const unsigned*>(hid16 + (size_t)b * HID)
                       + part * 32;
    const float* w2 = W2 + (size_t)v * HID + part * 64;
    float s = 0.f;
#pragma unroll
    for (int i = 0; i < 8; ++i) {
        u32x4 q = vldq(hp + i * 4);
#pragma unroll
        for (int h = 0; h < 4; ++h) {
            unsigned uw = q[h];
            float2 a2 = __half22float2(*reinterpret_cast<const __half2*>(&uw));
            const int k = i * 8 + h * 2;
            s += a2.x * w2[k] + a2.y * w2[k + 1];
        }
    }
    logred[v * 9 + part] = s;
    __syncthreads();
    if (t < 64) {
        float acc = b2[t];
#pragma unroll
        for (int k = 0; k < 8; ++k) acc += logred[t * 9 + k];
        out[((size_t)b * SLEN + trow) * VOCAB + t] = acc;
    }
    __syncthreads();
}

// attention for one batch row (blocks 0..63): full L=1024, writes chat16
__device__ __forceinline__ void phaseE(SMem& sm, int b, int tstep,
    const float* u, const __half* __restrict__ enc16, const __half* hid16,
    const float* __restrict__ W2, const float* __restrict__ b2,
    float* __restrict__ out, __half* chat16, float* logred)
{
    const int t = threadIdx.x;
    if (tstep > 0) logitsPhase(b, tstep - 1, hid16, W2, b2, out, logred);

    const int half = t >> 8;
    const int col  = t & 255;
    const int le   = t & 31;
    const int seg  = t >> 5;
    const int sq   = t & 15;
    const int sl   = (t >> 4) & 31;

    sm.a.u_s[t] = vld1(u + (size_t)b * HID + t);
    if (t == 0) { sm.a.msh[0] = -3.0e38f; sm.a.msh[1] = 0.f; sm.a.msh[2] = 0.f; }
    float vx = 0.f, vy = 0.f;

    const uint4* src = reinterpret_cast<const uint4*>(enc16 + (size_t)b * LLEN * HID);
    uint4 R[4];
#pragma unroll
    for (int p = 0; p < 4; ++p) R[p] = src[(size_t)sl * 64 + p * 16 + sq];
    __syncthreads();

    for (int blk = 0; blk < 32; ++blk) {
        {
            unsigned* dst = &sm.a.enc[sl * 261];
#pragma unroll
            for (int p = 0; p < 4; ++p) {
                const int c4 = (p * 16 + sq) * 4;
                dst[c4] = R[p].x; dst[c4+1] = R[p].y; dst[c4+2] = R[p].z; dst[c4+3] = R[p].w;
            }
        }
        __syncthreads();
        if (blk < 31) {
#pragma unroll
            for (int p = 0; p < 4; ++p)
                R[p] = src[((size_t)(blk + 1) * 32 + sl) * 64 + p * 16 + sq];
        }
        {   // scores
            float eacc = 0.f;
            const unsigned* er = &sm.a.enc[le * 261];
            const float* us = sm.a.u_s;
#pragma unroll
            for (int uu = 0; uu < 16; ++uu) {
                const int uo = seg * 16 + uu;
                unsigned uw = er[uo];
                float2 f2 = __half22float2(*reinterpret_cast<const __half2*>(&uw));
                eacc += us[2 * uo] * f2.x + us[2 * uo + 1] * f2.y;
            }
            sm.a.accs[seg][le] = eacc;
        }
        __syncthreads();
        if (t < 32) {
            float e = 0.f;
#pragma unroll
            for (int s2 = 0; s2 < 16; ++s2) e += sm.a.accs[s2][t];
            float bm = e;
#pragma unroll
            for (int off = 16; off > 0; off >>= 1) bm = fmaxf(bm, __shfl_xor(bm, off));
            const float m_old = sm.a.msh[0];
            const float m_new = fmaxf(m_old, bm);
            const float wl = __expf(e - m_new);
            float sw = wl;
#pragma unroll
            for (int off = 16; off > 0; off >>= 1) sw += __shfl_xor(sw, off);
            sm.a.w_s[t] = wl;
            if (t == 0) {
                const float sc = __expf(m_old - m_new);
                sm.a.msh[2] = sc;
                sm.a.msh[1] = sm.a.msh[1] * sc + sw;
                sm.a.msh[0] = m_new;
            }
        }
        __syncthreads();
        {
            const float sc = sm.a.msh[2];
            vx *= sc; vy *= sc;
#pragma unroll
            for (int ll = 0; ll < 16; ++ll) {
                const int l = half * 16 + ll;
                const float wl = sm.a.w_s[l];
                unsigned uw = sm.a.enc[l * 261 + col];
                float2 f2 = __half22float2(*reinterpret_cast<const __half2*>(&uw));
                vx += wl * f2.x; vy += wl * f2.y;
            }
        }
        __syncthreads();
    }
    if (half == 1) { sm.a.u_s[2 * col] = vx; sm.a.u_s[2 * col + 1] = vy; }
    __syncthreads();
    if (half == 0) {
        vx += sm.a.u_s[2 * col];
        vy += sm.a.u_s[2 * col + 1];
        const float inv = 1.f / sm.a.msh[1];
        *reinterpret_cast<volatile unsigned*>(
            reinterpret_cast<char*>(chat16) + (size_t)b * 1024 + col * 4)
            = packh2(vx * inv, vy * inv);
    }
}

// tail H: hid = relu(hpart + W1b'@chat)
__device__ __forceinline__ void phaseT(SMem& sm, int i0,
    const __half* chat16, const float* __restrict__ W1bp,
    const float* hpartPriv, __half* hid16, float (&htmp)[2][64],
    int wv, int lane)
{
    float acc[2] = {};
    const float* wp[2];
    wp[0] = W1bp + (size_t)i0 * HID;
    wp[1] = W1bp + (size_t)(i0 + 1) * HID;
    scanSeg<2, 2, true>(chat16, wp, acc, wv, lane);
    sm.r.red[wv][0][lane] = acc[0];
    sm.r.red[wv][1][lane] = acc[1];
    __syncthreads();
    const int t = threadIdx.x;
    if (t < 128) {
        const int b = t & 63, r = t >> 6;
        float s = hpartPriv[r * 64 + b];
#pragma unroll
        for (int w = 0; w < 8; ++w) s += sm.r.red[w][r][b];
        htmp[r][b] = fmaxf(s, 0.f);
    }
    __syncthreads();
    if (t < 64)
        *reinterpret_cast<volatile unsigned*>(
            reinterpret_cast<char*>(hid16) + (size_t)t * 1024 + i0 * 2)
            = packh2(htmp[0][t], htmp[1][t]);
}

// ---------------------------------------------------------------------------
__global__ __launch_bounds__(NT, 1)
void k_seq(const __half* __restrict__ xemb16, const __half* __restrict__ enc16,
           const float* __restrict__ aWih, const float* __restrict__ aWhh,
           const float* __restrict__ bihEff, const float* __restrict__ abhh,
           const float* __restrict__ rWih, const float* __restrict__ rWhh,
           const float* __restrict__ rbih, const float* __restrict__ rbhh,
           const float* __restrict__ Pm, const float* __restrict__ p0v,
           const float* __restrict__ W1, const float* __restrict__ b1eff,
           const float* __restrict__ Wp, const float* __restrict__ W1bp,
           const float* __restrict__ W2, const float* __restrict__ b2,
           __half* h0, __half* hs0, __half* hs1, __half* chat16, __half* hid16,
           float* u, float* out, unsigned* bar)
{
    __shared__ SMem sm;
    __shared__ float cPriv[3][128];
    __shared__ float hpartPriv[128];
    __shared__ float htmp[2][64];
    __shared__ float htmp2[2][64];
    __shared__ float logred[64 * 9];

    const int bid  = blockIdx.x;
    const int i0   = bid * 2;
    const int t0   = threadIdx.x;
    const int wv   = __builtin_amdgcn_readfirstlane(t0 >> 6);
    const int lane = t0 & 63;
    if (t0 < 128) { cPriv[0][t0] = 0.f; cPriv[1][t0] = 0.f; cPriv[2][t0] = 0.f;
                    hpartPriv[t0] = 0.f; }
    __syncthreads();

    unsigned nb = 0;
    for (int t = 0; t < SLEN; ++t) {
        const int par = t & 1;
        const __half* h0r  = h0  + (size_t)par * 32768;
        __half*       h0w  = h0  + (size_t)(par ^ 1) * 32768;
        const __half* hs0r = hs0 + (size_t)par * 32768;
        __half*       hs0w = hs0 + (size_t)(par ^ 1) * 32768;
        const __half* hs1r = hs1 + (size_t)par * 32768;
        __half*       hs1w = hs1 + (size_t)(par ^ 1) * 32768;

        phaseA(sm, i0, xemb16 + (size_t)t * BS * EMB, chat16, h0r,
               aWih, Wp, aWhh, W1bp, bihEff, abhh,
               cPriv[0], hpartPriv, h0w, hid16, htmp, htmp2, wv, lane);
        gridbar(bar, ++nb);
        phaseR(sm, i0, h0w, hs0r, rWih, rWhh, rbih, rbhh,
               cPriv[1], hs0w, htmp, wv, lane);
        gridbar(bar, ++nb);
        phaseR(sm, i0, hs0w, hs1r, rWih + (size_t)G4 * HID, rWhh + (size_t)G4 * HID,
               rbih + G4, rbhh + G4, cPriv[2], hs1w, htmp, wv, lane);
        gridbar(bar, ++nb);
        phaseD(sm, i0, hs1w, Pm, p0v, W1, b1eff, u, hpartPriv, wv, lane);
        gridbar(bar, ++nb);
        if (bid < BS)
            phaseE(sm, bid, t, u, enc16, hid16, W2, b2, out, chat16, logred);
        gridbar(bar, ++nb);
    }
    phaseT(sm, i0, chat16, W1bp, hpartPriv, hid16, htmp, wv, lane);
    gridbar(bar, ++nb);
    if (bid < BS) logitsPhase(bid, SLEN - 1, hid16, W2, b2, out, logred);
}

// ---------------------------------------------------------------------------
extern "C" void kernel_launch(void* const* d_in, const int* in_sizes, int n_in,
                              void* d_out, int out_size, void* d_ws, size_t ws_size,
                              hipStream_t stream)
{
    const int*   y    = (const int*)  d_in[0];
    const float* enc  = (const float*)d_in[1];
    const float* emb  = (const float*)d_in[2];
    const float* aWih = (const float*)d_in[3];
    const float* aWhh = (const float*)d_in[4];
    const float* abih = (const float*)d_in[5];
    const float* abhh = (const float*)d_in[6];
    const float* rWih = (const float*)d_in[7];
    const float* rWhh = (const float*)d_in[8];
    const float* rbih = (const float*)d_in[9];
    const float* rbhh = (const float*)d_in[10];
    const float* Wsw  = (const float*)d_in[11];
    const float* Wsb  = (const float*)d_in[12];
    const float* Whw  = (const float*)d_in[13];
    const float* Whb  = (const float*)d_in[14];
    const float* W1   = (const float*)d_in[15];
    const float* b1   = (const float*)d_in[16];
    const float* W2   = (const float*)d_in[17];
    const float* b2   = (const float*)d_in[18];
    float* out = (float*)d_out;

    char* base = (char*)d_ws;
    unsigned* bar = (unsigned*)base;                         base += 4096;
    // zero region (f16): h0(2), hs0(2), hs1(2), chat, hid = 8 x 64KB
    __half* h0     = (__half*)base;                          base += 2 * 65536;
    __half* hs0    = (__half*)base;                          base += 2 * 65536;
    __half* hs1    = (__half*)base;                          base += 2 * 65536;
    __half* chat16 = (__half*)base;                          base += 65536;
    __half* hid16  = (__half*)base;                          base += 65536;
    size_t zeroBytes = (size_t)(base - (char*)h0);
    float* u       = (float*)base;                           base += 131072;
    float* p0v     = (float*)base;                           base += 2048;
    float* bihEff  = (float*)base;                           base += 8192;
    float* b1eff   = (float*)base;                           base += 2048;
    float* Pm      = (float*)base;                           base += 1048576;
    float* Wp      = (float*)base;                           base += (size_t)G4 * HID * 4;
    float* W1bp    = (float*)base;                           base += (size_t)HID * HID * 4;
    __half* xemb16 = (__half*)base;                          base += (size_t)SLEN * BS * EMB * 2;
    __half* enc16  = (__half*)base;                          base += (size_t)BS * LLEN * HID * 2;
    size_t need = (size_t)(base - (char*)d_ws);
    if (ws_size < need) return;   // loud failure (output stays zero)

    hipMemsetAsync(bar, 0, 4096, stream);
    hipMemsetAsync(h0, 0, zeroBytes, stream);

    k_embed16<<<(SLEN * BS * EMB) / 256, 256, 0, stream>>>(y, emb, xemb16);
    k_cast<<<4096, 256, 0, stream>>>(enc, enc16, (BS * LLEN * HID) / 4);
    k_pmat<<<HID, 256, 0, stream>>>(Whw, Wsw, Wsb, Pm, p0v);
    k_fold<<<G4 + HID, 256, 0, stream>>>(aWih, W1, Whw, Whb, abih, b1,
                                         Wp, W1bp, bihEff, b1eff);

    k_seq<<<NB, NT, 0, stream>>>(xemb16, enc16,
        aWih, aWhh, bihEff, abhh, rWih, rWhh, rbih, rbhh,
        Pm, p0v, W1, b1eff, Wp, W1bp, W2, b2,
        h0, hs0, hs1, chat16, hid16, u, out, bar);
}

// Round 8
// 23205.173 us; speedup vs baseline: 1.7969x; 1.7969x over previous
//
#include <hip/hip_runtime.h>
#include <hip/hip_fp16.h>

#define HID   512
#define EMB   256
#define VOCAB 64
#define BS    64
#define SLEN  128
#define LLEN  1024
#define G4    2048
#define NB    256
#define NT    512

typedef unsigned u32x4 __attribute__((ext_vector_type(4)));

// ---------------------------------------------------------------------------
// MALL-coherent (cache-bypass) access helpers — proven R5/R6 protocol
__device__ __forceinline__ u32x4 vldq(const unsigned* p) {
    return *reinterpret_cast<const volatile u32x4*>(p);
}
__device__ __forceinline__ float vld1(const float* p) {
    return *reinterpret_cast<const volatile float*>(p);
}
__device__ __forceinline__ void vst1(float* p, float v) {
    *reinterpret_cast<volatile float*>(p) = v;
}
__device__ __forceinline__ void vstu(unsigned* p, unsigned v) {
    *reinterpret_cast<volatile unsigned*>(p) = v;
}
__device__ __forceinline__ unsigned packh2(float x, float y) {
    __half2 h = __floats2half2_rn(x, y);
    return *reinterpret_cast<unsigned*>(&h);
}

// ---------------------------------------------------------------------------
// LDS: As = double-buffered f32 tile [2][128][64]; red = reduction scratch
struct SCell { float As[2 * 8192]; float red[8][10][66]; };
struct SAttn { float u_s[512]; float w_s[32]; float msh[4];
               float accs[16][34]; unsigned enc[32 * 261]; };
struct SLog  { float red[16 * 33]; };
union SMem { SCell c; SAttn a; SLog lg; };

// ---------------------------------------------------------------------------
// grid barrier v5: flat slot array. Arrival = ONE relaxed store (no RMW).
// Every block's wave0 polls all 256 slots (4 coalesced loads/lane + __all).
// Visibility: vmcnt(0) drain at __syncthreads orders data stores before the
// slot store (proven R4-R6 write-through protocol).
__device__ __forceinline__ void gridbar(unsigned* bar, unsigned nb)
{
    __syncthreads();
    const int t = threadIdx.x;
    if (t < 64) {
        if (t == 0)
            __hip_atomic_store(bar + blockIdx.x, nb, __ATOMIC_RELAXED,
                               __HIP_MEMORY_SCOPE_AGENT);
        for (;;) {
            bool ok = true;
#pragma unroll
            for (int i = 0; i < 4; ++i) {
                unsigned v = __hip_atomic_load(bar + i * 64 + t, __ATOMIC_RELAXED,
                                               __HIP_MEMORY_SCOPE_AGENT);
                ok &= (v >= nb);
            }
            if (__all((int)ok)) break;
            __builtin_amdgcn_s_sleep(1);
        }
    }
    __syncthreads();
}

// ---------------------------------------------------------------------------
// one-time kernels
__global__ __launch_bounds__(256)
void k_embed16T(const int* __restrict__ y, const float* __restrict__ emb,
                __half* __restrict__ xemb16)   // [t][e][b] f16
{
    int i = blockIdx.x * 256 + threadIdx.x;
    int b  = i & 63;
    int e  = (i >> 6) & 255;
    int ts = i >> 14;
    xemb16[i] = __float2half(emb[y[b * SLEN + ts] * EMB + e]);
}

__global__ __launch_bounds__(256)
void k_cast(const float* __restrict__ src, __half* __restrict__ dst, int n4)
{
    int i = blockIdx.x * 256 + threadIdx.x;
    int stride = gridDim.x * 256;
    for (; i < n4; i += stride) {
        float4 v = reinterpret_cast<const float4*>(src)[i];
        reinterpret_cast<__half2*>(dst)[2 * i]     = __floats2half2_rn(v.x, v.y);
        reinterpret_cast<__half2*>(dst)[2 * i + 1] = __floats2half2_rn(v.z, v.w);
    }
}

__global__ __launch_bounds__(256)
void k_pmat(const float* __restrict__ Whw, const float* __restrict__ Wsw,
            const float* __restrict__ Wsb, float* __restrict__ P,
            float* __restrict__ p0)
{
    const int i = blockIdx.x;
    const int t = threadIdx.x;
    float a0 = 0.f, a1 = 0.f, ap = 0.f;
    for (int h = 0; h < HID; ++h) {
        float whi = Whw[h * HID + i];
        a0 += whi * Wsw[h * HID + t];
        a1 += whi * Wsw[h * HID + t + 256];
        ap += whi * Wsb[h];
    }
    P[i * HID + t]       = a0;
    P[i * HID + t + 256] = a1;
    if (t == 0) p0[i] = ap;
}

// fold ctx=Whw@chat+Whb into consumers (exact algebra, proven R7)
__global__ __launch_bounds__(256)
void k_fold(const float* __restrict__ aWih, const float* __restrict__ W1,
            const float* __restrict__ Whw, const float* __restrict__ Whb,
            const float* __restrict__ abih, const float* __restrict__ b1,
            float* __restrict__ Wp, float* __restrict__ W1bp,
            float* __restrict__ bihEff, float* __restrict__ b1eff)
{
    const int r = blockIdx.x;
    const int t = threadIdx.x;
    __shared__ float ssrc[512];
    const float* src;
    float* dst;
    if (r < G4) { src = aWih + (size_t)r * (EMB + HID) + EMB; dst = Wp + (size_t)r * HID; }
    else        { src = W1 + (size_t)(r - G4) * (2 * HID) + HID; dst = W1bp + (size_t)(r - G4) * HID; }
    ssrc[t]       = src[t];
    ssrc[t + 256] = src[t + 256];
    __syncthreads();
    float a0 = 0.f, a1 = 0.f;
    for (int h = 0; h < HID; ++h) {
        const float s = ssrc[h];
        a0 += s * Whw[h * HID + t];
        a1 += s * Whw[h * HID + t + 256];
    }
    dst[t]       = a0;
    dst[t + 256] = a1;
    if (t == 0) {
        float bb = 0.f;
        for (int h = 0; h < HID; ++h) bb += ssrc[h] * Whb[h];
        if (r < G4) bihEff[r] = abih[r] + bb;
        else        b1eff[r - G4] = b1[r - G4] + bb;
    }
}

// ---------------------------------------------------------------------------
// staged transposed-f16 scan: activation A is [NTILES*128 k][64 b] f16.
// Stage 16KB tile coalesced -> unpack once to f32 LDS [128][64] -> conflict-
// free compute reads (lane=b, 2-way = free). Double-buffered, 1 sync/tile.
template<int NTILES, int NR, bool VOL>
__device__ __forceinline__ void segScanT(float* As, const __half* A,
    const float* const* w, float* acc, int wv, int lane)
{
    const int t = threadIdx.x;
    const unsigned* ga = reinterpret_cast<const unsigned*>(A) + (size_t)t * 8;
    const int kRow = t >> 2;
    const int c0   = (t & 3) * 16;
    u32x4 Ra[2], Rb[2];

#define LOADT(R, j) do { const unsigned* _p = ga + (size_t)(j) * 4096;            \
        if (VOL) { R[0] = vldq(_p); R[1] = vldq(_p + 4); }                        \
        else { R[0] = *reinterpret_cast<const u32x4*>(_p);                        \
               R[1] = *reinterpret_cast<const u32x4*>(_p + 4); } } while (0)

    LOADT(Ra, 0);
    __syncthreads();                      // handoff: prior users of As done
#pragma unroll
    for (int j = 0; j < NTILES; ++j) {
        float* dst = As + (j & 1) * 8192 + kRow * 64 + c0;
        const u32x4* R = (j & 1) ? Rb : Ra;
#pragma unroll
        for (int q = 0; q < 2; ++q)
#pragma unroll
            for (int h = 0; h < 4; ++h) {
                unsigned uw = R[q][h];
                float2 f2 = __half22float2(*reinterpret_cast<const __half2*>(&uw));
                dst[(q * 4 + h) * 2]     = f2.x;
                dst[(q * 4 + h) * 2 + 1] = f2.y;
            }
        if (j + 1 < NTILES) { if (j & 1) { LOADT(Ra, j + 1); } else { LOADT(Rb, j + 1); } }
        __syncthreads();
        const float* as = As + (j & 1) * 8192 + (wv * 16) * 64 + lane;
#pragma unroll
        for (int kk = 0; kk < 16; ++kk) {
            const float a = as[kk * 64];
            const int k = j * 128 + wv * 16 + kk;
#pragma unroll
            for (int r = 0; r < NR; ++r)
                acc[r] += a * w[r][k];
        }
    }
#undef LOADT
}

// coalesced h-state pack-write: rows i0,i0+1 of [k][b] f16 = 64 u32 burst
__device__ __forceinline__ void packRows(__half* dstH, int i0, const float (&htmp)[2][64])
{
    const int t = threadIdx.x;
    if (t < 64) {
        const int hl = t >> 5;
        const int b2 = (t & 31) * 2;
        vstu(reinterpret_cast<unsigned*>(dstH) + (size_t)(i0 + hl) * 32 + (t & 31),
             packh2(htmp[hl][b2], htmp[hl][b2 + 1]));
    }
}

// ---------------------------------------------------------------------------
// phase A: attention-input LSTM cell + fused hid(t-1) finish
__device__ __forceinline__ void phaseA(SMem& sm, int i0,
    const __half* xT, const __half* chatT, const __half* h0rT,
    const float* __restrict__ aWih, const float* __restrict__ Wp,
    const float* __restrict__ aWhh, const float* __restrict__ W1bp,
    const float* __restrict__ bihEff, const float* __restrict__ abhh,
    float* cp, const float* hpartPriv, __half* h0wT, float* hid,
    float (&htmp)[2][64], int wv, int lane)
{
    float acc[10] = {};
    {   // x segment (k=256)
        const float* w8[8];
#pragma unroll
        for (int r = 0; r < 8; ++r)
            w8[r] = aWih + (size_t)((r >> 1) * HID + i0 + (r & 1)) * (EMB + HID);
        segScanT<2, 8, false>(sm.c.As, xT, w8, acc, wv, lane);
    }
    {   // chat segment (folded ctx weights) + fused W1bp rows
        const float* w10[10];
#pragma unroll
        for (int r = 0; r < 8; ++r)
            w10[r] = Wp + (size_t)((r >> 1) * HID + i0 + (r & 1)) * HID;
        w10[8] = W1bp + (size_t)i0 * HID;
        w10[9] = W1bp + (size_t)(i0 + 1) * HID;
        segScanT<4, 10, true>(sm.c.As, chatT, w10, acc, wv, lane);
    }
    {   // recurrent h segment
        const float* w8[8];
#pragma unroll
        for (int r = 0; r < 8; ++r)
            w8[r] = aWhh + (size_t)((r >> 1) * HID + i0 + (r & 1)) * HID;
        segScanT<4, 8, true>(sm.c.As, h0rT, w8, acc, wv, lane);
    }
#pragma unroll
    for (int r = 0; r < 10; ++r) sm.c.red[wv][r][lane] = acc[r];
    __syncthreads();
    const int t = threadIdx.x;
    if (t < 128) {
        const int b = t & 63, hl = t >> 6;
        float gs[4];
#pragma unroll
        for (int g = 0; g < 4; ++g) {
            const int row = g * HID + i0 + hl;
            float s = bihEff[row] + abhh[row];
#pragma unroll
            for (int w = 0; w < 8; ++w) s += sm.c.red[w][g * 2 + hl][b];
            gs[g] = s;
        }
        const float ig = 1.f / (1.f + __expf(-gs[0]));
        const float fg = 1.f / (1.f + __expf(-gs[1]));
        const float gg = tanhf(gs[2]);
        const float og = 1.f / (1.f + __expf(-gs[3]));
        const float c2 = fg * cp[hl * 64 + b] + ig * gg;
        cp[hl * 64 + b] = c2;
        htmp[hl][b] = og * tanhf(c2);
    } else if (t < 256) {
        const int b = t & 63, hl = (t >> 6) - 2;
        float s = hpartPriv[hl * 64 + b];
#pragma unroll
        for (int w = 0; w < 8; ++w) s += sm.c.red[w][8 + hl][b];
        vst1(hid + (size_t)b * HID + i0 + hl, fmaxf(s, 0.f));
    }
    __syncthreads();
    packRows(h0wT, i0, htmp);
}

// phases B, C: plain rnn LSTM cell
__device__ __forceinline__ void phaseR(SMem& sm, int i0,
    const __half* inT, const __half* recT,
    const float* __restrict__ Wih, const float* __restrict__ Whh,
    const float* __restrict__ bih, const float* __restrict__ bhh,
    float* cp, __half* hOutT, float (&htmp)[2][64], int wv, int lane)
{
    float acc[8] = {};
    {
        const float* w8[8];
#pragma unroll
        for (int r = 0; r < 8; ++r)
            w8[r] = Wih + (size_t)((r >> 1) * HID + i0 + (r & 1)) * HID;
        segScanT<4, 8, true>(sm.c.As, inT, w8, acc, wv, lane);
    }
    {
        const float* w8[8];
#pragma unroll
        for (int r = 0; r < 8; ++r)
            w8[r] = Whh + (size_t)((r >> 1) * HID + i0 + (r & 1)) * HID;
        segScanT<4, 8, true>(sm.c.As, recT, w8, acc, wv, lane);
    }
#pragma unroll
    for (int r = 0; r < 8; ++r) sm.c.red[wv][r][lane] = acc[r];
    __syncthreads();
    const int t = threadIdx.x;
    if (t < 128) {
        const int b = t & 63, hl = t >> 6;
        float gs[4];
#pragma unroll
        for (int g = 0; g < 4; ++g) {
            const int row = g * HID + i0 + hl;
            float s = bih[row] + bhh[row];
#pragma unroll
            for (int w = 0; w < 8; ++w) s += sm.c.red[w][g * 2 + hl][b];
            gs[g] = s;
        }
        const float ig = 1.f / (1.f + __expf(-gs[0]));
        const float fg = 1.f / (1.f + __expf(-gs[1]));
        const float gg = tanhf(gs[2]);
        const float og = 1.f / (1.f + __expf(-gs[3]));
        const float c2 = fg * cp[hl * 64 + b] + ig * gg;
        cp[hl * 64 + b] = c2;
        htmp[hl][b] = og * tanhf(c2);
    }
    __syncthreads();
    packRows(hOutT, i0, htmp);
}

// logits for one step (block -> (b, 16 v's)); uses lg.red (As-overlap safe)
__device__ __forceinline__ void logitsPhase(SMem& sm, int bid,
    const float* hid, const float* __restrict__ W2,
    const float* __restrict__ b2, float* __restrict__ out, int tstep)
{
    const int t  = threadIdx.x;
    const int b  = bid & 63;
    const int vg = bid >> 6;
    const int vp = t >> 5;
    const int kk = t & 31;
    float hreg[16];
    const float* hp = hid + (size_t)b * HID + kk * 16;
#pragma unroll
    for (int k = 0; k < 16; ++k) hreg[k] = vld1(hp + k);
    const float* w = W2 + (size_t)(vg * 16 + vp) * HID + kk * 16;
    float s = 0.f;
#pragma unroll
    for (int k = 0; k < 16; ++k) s += hreg[k] * w[k];
    __syncthreads();
    sm.lg.red[vp * 33 + kk] = s;
    __syncthreads();
    if (t < 16) {
        float acc = b2[vg * 16 + t];
#pragma unroll
        for (int k = 0; k < 32; ++k) acc += sm.lg.red[t * 33 + k];
        out[((size_t)b * SLEN + tstep) * VOCAB + vg * 16 + t] = acc;
    }
}

// phase D: logits(t-1) + dual GEMV (u -> global f32, hpart -> LDS)
__device__ __forceinline__ void phaseD(SMem& sm, int i0,
    const __half* prevT, const float* __restrict__ Pm,
    const float* __restrict__ p0v, const float* __restrict__ W1,
    const float* __restrict__ b1eff, float* u, float* hpartPriv,
    int wv, int lane)
{
    float acc[4] = {};
    const float* w4[4];
    w4[0] = Pm + (size_t)i0 * HID;
    w4[1] = Pm + (size_t)(i0 + 1) * HID;
    w4[2] = W1 + (size_t)i0 * (2 * HID);
    w4[3] = W1 + (size_t)(i0 + 1) * (2 * HID);
    segScanT<4, 4, true>(sm.c.As, prevT, w4, acc, wv, lane);
#pragma unroll
    for (int r = 0; r < 4; ++r) sm.c.red[wv][r][lane] = acc[r];
    __syncthreads();
    const int t = threadIdx.x;
    if (t < 256) {
        const int b = t & 63, r = t >> 6;
        float s = 0.f;
#pragma unroll
        for (int w = 0; w < 8; ++w) s += sm.c.red[w][r][b];
        if (r < 2) vst1(u + (size_t)b * HID + i0 + r, s + p0v[i0 + r]);
        else       hpartPriv[(r - 2) * 64 + b] = s + b1eff[i0 + r - 2];
    }
}

// phase E: attention partials (R6-proven: 4 chunks x 64 b, f16 LDS-staged)
__device__ __forceinline__ void phaseE(SMem& sm, int bid,
    const float* u, const __half* __restrict__ enc16,
    float* pm, float* ps, float* pv)
{
    const int t    = threadIdx.x;
    const int b    = bid >> 2;
    const int ch   = bid & 3;
    const int half = t >> 8;
    const int col  = t & 255;
    const int le   = t & 31;
    const int seg  = t >> 5;
    const int sq   = t & 15;
    const int sl   = (t >> 4) & 31;

    sm.a.u_s[t] = vld1(u + (size_t)b * HID + t);
    if (t == 0) { sm.a.msh[0] = -3.0e38f; sm.a.msh[1] = 0.f; sm.a.msh[2] = 0.f; }
    float vx = 0.f, vy = 0.f;

    const uint4* src = reinterpret_cast<const uint4*>(enc16 + ((size_t)b * LLEN + ch * 256) * HID);
    uint4 R[4];
#pragma unroll
    for (int p = 0; p < 4; ++p) R[p] = src[(size_t)sl * 64 + p * 16 + sq];
    __syncthreads();

    for (int blk = 0; blk < 8; ++blk) {
        {
            unsigned* dst = &sm.a.enc[sl * 261];
#pragma unroll
            for (int p = 0; p < 4; ++p) {
                const int c4 = (p * 16 + sq) * 4;
                dst[c4] = R[p].x; dst[c4+1] = R[p].y; dst[c4+2] = R[p].z; dst[c4+3] = R[p].w;
            }
        }
        __syncthreads();
        if (blk < 7) {
#pragma unroll
            for (int p = 0; p < 4; ++p)
                R[p] = src[((size_t)(blk + 1) * 32 + sl) * 64 + p * 16 + sq];
        }
        {   // scores
            float eacc = 0.f;
            const unsigned* er = &sm.a.enc[le * 261];
            const float* us = sm.a.u_s;
#pragma unroll
            for (int uu = 0; uu < 16; ++uu) {
                const int uo = seg * 16 + uu;
                unsigned uw = er[uo];
                float2 f2 = __half22float2(*reinterpret_cast<const __half2*>(&uw));
                eacc += us[2 * uo] * f2.x + us[2 * uo + 1] * f2.y;
            }
            sm.a.accs[seg][le] = eacc;
        }
        __syncthreads();
        if (t < 32) {
            float e = 0.f;
#pragma unroll
            for (int s2 = 0; s2 < 16; ++s2) e += sm.a.accs[s2][t];
            float bm = e;
#pragma unroll
            for (int off = 16; off > 0; off >>= 1) bm = fmaxf(bm, __shfl_xor(bm, off));
            const float m_old = sm.a.msh[0];
            const float m_new = fmaxf(m_old, bm);
            const float wl = __expf(e - m_new);
            float sw = wl;
#pragma unroll
            for (int off = 16; off > 0; off >>= 1) sw += __shfl_xor(sw, off);
            sm.a.w_s[t] = wl;
            if (t == 0) {
                const float sc = __expf(m_old - m_new);
                sm.a.msh[2] = sc;
                sm.a.msh[1] = sm.a.msh[1] * sc + sw;
                sm.a.msh[0] = m_new;
            }
        }
        __syncthreads();
        {
            const float sc = sm.a.msh[2];
            vx *= sc; vy *= sc;
#pragma unroll
            for (int ll = 0; ll < 16; ++ll) {
                const int l = half * 16 + ll;
                const float wl = sm.a.w_s[l];
                unsigned uw = sm.a.enc[l * 261 + col];
                float2 f2 = __half22float2(*reinterpret_cast<const __half2*>(&uw));
                vx += wl * f2.x; vy += wl * f2.y;
            }
        }
        __syncthreads();
    }
    if (half == 1) { sm.a.u_s[2 * col] = vx; sm.a.u_s[2 * col + 1] = vy; }
    __syncthreads();
    if (half == 0) {
        vx += sm.a.u_s[2 * col];
        vy += sm.a.u_s[2 * col + 1];
        const int pc = b * 4 + ch;
        vst1(pv + (size_t)pc * HID + 2 * col,     vx);
        vst1(pv + (size_t)pc * HID + 2 * col + 1, vy);
        if (t == 0) { vst1(pm + pc, sm.a.msh[0]); vst1(ps + pc, sm.a.msh[1]); }
    }
}

// phase F: combine partials -> normalized chat, write transposed f16 rows
__device__ __forceinline__ void phaseF(int bid,
    const float* pm, const float* ps, const float* pv, __half* chatT)
{
    const int t = threadIdx.x;
    if (t < 128) {
        const int b = t & 63;
        const int j = bid * 2 + (t >> 6);
        float m[4], sd[4], pvv[4];
#pragma unroll
        for (int c = 0; c < 4; ++c) m[c]   = vld1(pm + b * 4 + c);
#pragma unroll
        for (int c = 0; c < 4; ++c) sd[c]  = vld1(ps + b * 4 + c);
#pragma unroll
        for (int c = 0; c < 4; ++c) pvv[c] = vld1(pv + (size_t)(b * 4 + c) * HID + j);
        float M = fmaxf(fmaxf(m[0], m[1]), fmaxf(m[2], m[3]));
        float den = 0.f, num = 0.f;
#pragma unroll
        for (int c = 0; c < 4; ++c) {
            float e = __expf(m[c] - M);
            den += e * sd[c]; num += e * pvv[c];
        }
        float v = num / den;
        float vn = __shfl_down(v, 1);
        if ((b & 1) == 0)
            vstu(reinterpret_cast<unsigned*>(chatT) + (size_t)j * 32 + (b >> 1),
                 packh2(v, vn));
    }
}

// tail: hid(S-1) = relu(hpart + W1bp@chat)
__device__ __forceinline__ void phaseT(SMem& sm, int i0,
    const __half* chatT, const float* __restrict__ W1bp,
    const float* hpartPriv, float* hid, int wv, int lane)
{
    float acc[2] = {};
    const float* w2[2];
    w2[0] = W1bp + (size_t)i0 * HID;
    w2[1] = W1bp + (size_t)(i0 + 1) * HID;
    segScanT<4, 2, true>(sm.c.As, chatT, w2, acc, wv, lane);
    sm.c.red[wv][0][lane] = acc[0];
    sm.c.red[wv][1][lane] = acc[1];
    __syncthreads();
    const int t = threadIdx.x;
    if (t < 128) {
        const int b = t & 63, r = t >> 6;
        float s = hpartPriv[r * 64 + b];
#pragma unroll
        for (int w = 0; w < 8; ++w) s += sm.c.red[w][r][b];
        vst1(hid + (size_t)b * HID + i0 + r, fmaxf(s, 0.f));
    }
}

// ---------------------------------------------------------------------------
__global__ __launch_bounds__(NT, 1)
void k_seq(const __half* __restrict__ xemb16, const __half* __restrict__ enc16,
           const float* __restrict__ aWih, const float* __restrict__ aWhh,
           const float* __restrict__ bihEff, const float* __restrict__ abhh,
           const float* __restrict__ rWih, const float* __restrict__ rWhh,
           const float* __restrict__ rbih, const float* __restrict__ rbhh,
           const float* __restrict__ Pm, const float* __restrict__ p0v,
           const float* __restrict__ W1, const float* __restrict__ b1eff,
           const float* __restrict__ Wp, const float* __restrict__ W1bp,
           const float* __restrict__ W2, const float* __restrict__ b2,
           __half* h0T, __half* hs0T, __half* hs1T, __half* chatT,
           float* u, float* hid, float* pv, float* pm, float* ps,
           float* out, unsigned* bar)
{
    __shared__ SMem sm;
    __shared__ float cPriv[3][128];
    __shared__ float hpartPriv[128];
    __shared__ float htmp[2][64];

    const int bid  = blockIdx.x;
    const int i0   = bid * 2;
    const int t0   = threadIdx.x;
    const int wv   = __builtin_amdgcn_readfirstlane(t0 >> 6);
    const int lane = t0 & 63;
    if (t0 < 128) { cPriv[0][t0] = 0.f; cPriv[1][t0] = 0.f; cPriv[2][t0] = 0.f;
                    hpartPriv[t0] = 0.f; }
    __syncthreads();

    unsigned nb = 0;
    for (int t = 0; t < SLEN; ++t) {
        const int par = t & 1;
        const __half* h0r  = h0T  + (size_t)par * 32768;
        __half*       h0w  = h0T  + (size_t)(par ^ 1) * 32768;
        const __half* hs0r = hs0T + (size_t)par * 32768;
        __half*       hs0w = hs0T + (size_t)(par ^ 1) * 32768;
        const __half* hs1r = hs1T + (size_t)par * 32768;
        __half*       hs1w = hs1T + (size_t)(par ^ 1) * 32768;

        phaseA(sm, i0, xemb16 + (size_t)t * BS * EMB, chatT, h0r,
               aWih, Wp, aWhh, W1bp, bihEff, abhh,
               cPriv[0], hpartPriv, h0w, hid, htmp, wv, lane);
        gridbar(bar, ++nb);
        phaseR(sm, i0, h0w, hs0r, rWih, rWhh, rbih, rbhh,
               cPriv[1], hs0w, htmp, wv, lane);
        gridbar(bar, ++nb);
        phaseR(sm, i0, hs0w, hs1r, rWih + (size_t)G4 * HID, rWhh + (size_t)G4 * HID,
               rbih + G4, rbhh + G4, cPriv[2], hs1w, htmp, wv, lane);
        gridbar(bar, ++nb);
        if (t > 0) logitsPhase(sm, bid, hid, W2, b2, out, t - 1);
        phaseD(sm, i0, hs1w, Pm, p0v, W1, b1eff, u, hpartPriv, wv, lane);
        gridbar(bar, ++nb);
        phaseE(sm, bid, u, enc16, pm, ps, pv);
        gridbar(bar, ++nb);
        phaseF(bid, pm, ps, pv, chatT);
        gridbar(bar, ++nb);
    }
    phaseT(sm, i0, chatT, W1bp, hpartPriv, hid, wv, lane);
    gridbar(bar, ++nb);
    logitsPhase(sm, bid, hid, W2, b2, out, SLEN - 1);
}

// ---------------------------------------------------------------------------
extern "C" void kernel_launch(void* const* d_in, const int* in_sizes, int n_in,
                              void* d_out, int out_size, void* d_ws, size_t ws_size,
                              hipStream_t stream)
{
    const int*   y    = (const int*)  d_in[0];
    const float* enc  = (const float*)d_in[1];
    const float* emb  = (const float*)d_in[2];
    const float* aWih = (const float*)d_in[3];
    const float* aWhh = (const float*)d_in[4];
    const float* abih = (const float*)d_in[5];
    const float* abhh = (const float*)d_in[6];
    const float* rWih = (const float*)d_in[7];
    const float* rWhh = (const float*)d_in[8];
    const float* rbih = (const float*)d_in[9];
    const float* rbhh = (const float*)d_in[10];
    const float* Wsw  = (const float*)d_in[11];
    const float* Wsb  = (const float*)d_in[12];
    const float* Whw  = (const float*)d_in[13];
    const float* Whb  = (const float*)d_in[14];
    const float* W1   = (const float*)d_in[15];
    const float* b1   = (const float*)d_in[16];
    const float* W2   = (const float*)d_in[17];
    const float* b2   = (const float*)d_in[18];
    float* out = (float*)d_out;

    char* base = (char*)d_ws;
    unsigned* bar = (unsigned*)base;                 base += 4096;
    // zero region (f16 transposed state): h0(2), hs0(2), hs1(2), chat = 448KB
    __half* h0T   = (__half*)base;                   base += 2 * 65536;
    __half* hs0T  = (__half*)base;                   base += 2 * 65536;
    __half* hs1T  = (__half*)base;                   base += 2 * 65536;
    __half* chatT = (__half*)base;                   base += 65536;
    size_t zeroBytes = (size_t)(base - (char*)h0T);
    float* u      = (float*)base;                    base += 131072;
    float* hid    = (float*)base;                    base += 131072;
    float* pv     = (float*)base;                    base += 524288;
    float* pm     = (float*)base;                    base += 1024;
    float* ps     = (float*)base;                    base += 1024;
    float* Pm     = (float*)base;                    base += 1048576;
    float* p0v    = (float*)base;                    base += 2048;
    float* Wp     = (float*)base;                    base += (size_t)G4 * HID * 4;
    float* W1bp   = (float*)base;                    base += (size_t)HID * HID * 4;
    float* bihEff = (float*)base;                    base += 8192;
    float* b1eff  = (float*)base;                    base += 2048;
    __half* xemb16 = (__half*)base;                  base += (size_t)SLEN * BS * EMB * 2;
    __half* enc16  = (__half*)base;                  base += (size_t)BS * LLEN * HID * 2;
    size_t need = (size_t)(base - (char*)d_ws);
    if (ws_size < need) return;   // loud failure (output stays zero)

    hipMemsetAsync(bar, 0, 4096, stream);
    hipMemsetAsync(h0T, 0, zeroBytes, stream);

    k_embed16T<<<(SLEN * BS * EMB) / 256, 256, 0, stream>>>(y, emb, xemb16);
    k_cast<<<4096, 256, 0, stream>>>(enc, enc16, (BS * LLEN * HID) / 4);
    k_pmat<<<HID, 256, 0, stream>>>(Whw, Wsw, Wsb, Pm, p0v);
    k_fold<<<G4 + HID, 256, 0, stream>>>(aWih, W1, Whw, Whb, abih, b1,
                                         Wp, W1bp, bihEff, b1eff);

    k_seq<<<NB, NT, 0, stream>>>(xemb16, enc16,
        aWih, aWhh, bihEff, abhh, rWih, rWhh, rbih, rbhh,
        Pm, p0v, W1, b1eff, Wp, W1bp, W2, b2,
        h0T, hs0T, hs1T, chatT, u, hid, pv, pm, ps, out, bar);
}

// Round 9
// 18649.298 us; speedup vs baseline: 2.2359x; 1.2443x over previous
//
#include <hip/hip_runtime.h>
#include <hip/hip_fp16.h>

#define HID   512
#define EMB   256
#define VOCAB 64
#define BS    64
#define SLEN  128
#define LLEN  1024
#define G4    2048
#define NB    256
#define NT    512
#define ASTR  66          // unpacked-tile row stride (f32): 2-way banks, 8B-aligned
#define ASZ   (128 * ASTR)

typedef unsigned u32x4 __attribute__((ext_vector_type(4)));

// ---------------------------------------------------------------------------
// MALL-coherent (cache-bypass) access helpers — proven R5/R6 protocol
__device__ __forceinline__ u32x4 vldq(const unsigned* p) {
    return *reinterpret_cast<const volatile u32x4*>(p);
}
__device__ __forceinline__ float vld1(const float* p) {
    return *reinterpret_cast<const volatile float*>(p);
}
__device__ __forceinline__ void vst1(float* p, float v) {
    *reinterpret_cast<volatile float*>(p) = v;
}
__device__ __forceinline__ void vstu(unsigned* p, unsigned v) {
    *reinterpret_cast<volatile unsigned*>(p) = v;
}
__device__ __forceinline__ unsigned packh2(float x, float y) {
    __half2 h = __floats2half2_rn(x, y);
    return *reinterpret_cast<unsigned*>(&h);
}

// ---------------------------------------------------------------------------
// LDS: As = double-buffered f32 tile [2][128][ASTR]; red = reduction scratch
struct SCell { float As[2 * ASZ]; float red[8][10][66]; };
struct SAttn { float u_s[512]; float w_s[32]; float msh[4];
               float accs[16][34]; unsigned enc[32 * 261]; };
struct SLog  { float red[16 * 33]; };
union SMem { SCell c; SAttn a; SLog lg; };

// ---------------------------------------------------------------------------
// grid barrier v5: flat slot array. Arrival = ONE relaxed store (no RMW).
// Every block's wave0 polls all 256 slots (4 coalesced loads/lane + __all).
__device__ __forceinline__ void gridbar(unsigned* bar, unsigned nb)
{
    __syncthreads();
    const int t = threadIdx.x;
    if (t < 64) {
        if (t == 0)
            __hip_atomic_store(bar + blockIdx.x, nb, __ATOMIC_RELAXED,
                               __HIP_MEMORY_SCOPE_AGENT);
        for (;;) {
            bool ok = true;
#pragma unroll
            for (int i = 0; i < 4; ++i) {
                unsigned v = __hip_atomic_load(bar + i * 64 + t, __ATOMIC_RELAXED,
                                               __HIP_MEMORY_SCOPE_AGENT);
                ok &= (v >= nb);
            }
            if (__all((int)ok)) break;
            __builtin_amdgcn_s_sleep(1);
        }
    }
    __syncthreads();
}

// ---------------------------------------------------------------------------
// one-time kernels
__global__ __launch_bounds__(256)
void k_embed16T(const int* __restrict__ y, const float* __restrict__ emb,
                __half* __restrict__ xemb16)   // [t][e][b] f16
{
    int i = blockIdx.x * 256 + threadIdx.x;
    int b  = i & 63;
    int e  = (i >> 6) & 255;
    int ts = i >> 14;
    xemb16[i] = __float2half(emb[y[b * SLEN + ts] * EMB + e]);
}

__global__ __launch_bounds__(256)
void k_cast(const float* __restrict__ src, __half* __restrict__ dst, int n4)
{
    int i = blockIdx.x * 256 + threadIdx.x;
    int stride = gridDim.x * 256;
    for (; i < n4; i += stride) {
        float4 v = reinterpret_cast<const float4*>(src)[i];
        reinterpret_cast<__half2*>(dst)[2 * i]     = __floats2half2_rn(v.x, v.y);
        reinterpret_cast<__half2*>(dst)[2 * i + 1] = __floats2half2_rn(v.z, v.w);
    }
}

__global__ __launch_bounds__(256)
void k_pmat(const float* __restrict__ Whw, const float* __restrict__ Wsw,
            const float* __restrict__ Wsb, float* __restrict__ P,
            float* __restrict__ p0)
{
    const int i = blockIdx.x;
    const int t = threadIdx.x;
    float a0 = 0.f, a1 = 0.f, ap = 0.f;
    for (int h = 0; h < HID; ++h) {
        float whi = Whw[h * HID + i];
        a0 += whi * Wsw[h * HID + t];
        a1 += whi * Wsw[h * HID + t + 256];
        ap += whi * Wsb[h];
    }
    P[i * HID + t]       = a0;
    P[i * HID + t + 256] = a1;
    if (t == 0) p0[i] = ap;
}

// fold ctx=Whw@chat+Whb into consumers (exact algebra, proven R7/R8)
__global__ __launch_bounds__(256)
void k_fold(const float* __restrict__ aWih, const float* __restrict__ W1,
            const float* __restrict__ Whw, const float* __restrict__ Whb,
            const float* __restrict__ abih, const float* __restrict__ b1,
            float* __restrict__ Wp, float* __restrict__ W1bp,
            float* __restrict__ bihEff, float* __restrict__ b1eff)
{
    const int r = blockIdx.x;
    const int t = threadIdx.x;
    __shared__ float ssrc[512];
    const float* src;
    float* dst;
    if (r < G4) { src = aWih + (size_t)r * (EMB + HID) + EMB; dst = Wp + (size_t)r * HID; }
    else        { src = W1 + (size_t)(r - G4) * (2 * HID) + HID; dst = W1bp + (size_t)(r - G4) * HID; }
    ssrc[t]       = src[t];
    ssrc[t + 256] = src[t + 256];
    __syncthreads();
    float a0 = 0.f, a1 = 0.f;
    for (int h = 0; h < HID; ++h) {
        const float s = ssrc[h];
        a0 += s * Whw[h * HID + t];
        a1 += s * Whw[h * HID + t + 256];
    }
    dst[t]       = a0;
    dst[t + 256] = a1;
    if (t == 0) {
        float bb = 0.f;
        for (int h = 0; h < HID; ++h) bb += ssrc[h] * Whb[h];
        if (r < G4) bihEff[r] = abih[r] + bb;
        else        b1eff[r - G4] = b1[r - G4] + bb;
    }
}

// ---------------------------------------------------------------------------
// staged transposed-f16 scan: activation A is [NTILES*128 k][64 b] f16.
// Stage 16KB tile coalesced -> unpack once to f32 LDS [128][ASTR] (2-way
// banks on write AND read = free) -> compute. Double-buffered, 1 sync/tile.
template<int NTILES, int NR, bool VOL>
__device__ __forceinline__ void segScanT(float* As, const __half* A,
    const float* const* w, float* acc, int wv, int lane)
{
    const int t = threadIdx.x;
    const unsigned* ga = reinterpret_cast<const unsigned*>(A) + (size_t)t * 8;
    const int kRow = t >> 2;
    const int c0   = (t & 3) * 16;
    u32x4 Ra[2], Rb[2];

#define LOADT(R, j) do { const unsigned* _p = ga + (size_t)(j) * 4096;            \
        if (VOL) { R[0] = vldq(_p); R[1] = vldq(_p + 4); }                        \
        else { R[0] = *reinterpret_cast<const u32x4*>(_p);                        \
               R[1] = *reinterpret_cast<const u32x4*>(_p + 4); } } while (0)

    LOADT(Ra, 0);
    __syncthreads();                      // handoff: prior users of As done
#pragma unroll
    for (int j = 0; j < NTILES; ++j) {
        float2* dst = reinterpret_cast<float2*>(As + (j & 1) * ASZ + kRow * ASTR + c0);
        const u32x4* R = (j & 1) ? Rb : Ra;
#pragma unroll
        for (int q = 0; q < 2; ++q)
#pragma unroll
            for (int h = 0; h < 4; ++h) {
                unsigned uw = R[q][h];
                dst[q * 4 + h] = __half22float2(*reinterpret_cast<const __half2*>(&uw));
            }
        if (j + 1 < NTILES) { if (j & 1) { LOADT(Ra, j + 1); } else { LOADT(Rb, j + 1); } }
        __syncthreads();
        const float* as = As + (j & 1) * ASZ + (wv * 16) * ASTR + lane;
#pragma unroll
        for (int kk = 0; kk < 16; ++kk) {
            const float a = as[kk * ASTR];
            const int k = j * 128 + wv * 16 + kk;
#pragma unroll
            for (int r = 0; r < NR; ++r)
                acc[r] += a * w[r][k];
        }
    }
#undef LOADT
}

// coalesced h-state pack-write: rows i0,i0+1 of [k][b] f16 = 64 u32 burst
__device__ __forceinline__ void packRows(__half* dstH, int i0, const float (&htmp)[2][64])
{
    const int t = threadIdx.x;
    if (t < 64) {
        const int hl = t >> 5;
        const int b2 = (t & 31) * 2;
        vstu(reinterpret_cast<unsigned*>(dstH) + (size_t)(i0 + hl) * 32 + (t & 31),
             packh2(htmp[hl][b2], htmp[hl][b2 + 1]));
    }
}

// ---------------------------------------------------------------------------
// phase A: attention-input LSTM cell + fused hid(t-1) finish
__device__ __forceinline__ void phaseA(SMem& sm, int i0,
    const __half* xT, const __half* chatT, const __half* h0rT,
    const float* __restrict__ aWih, const float* __restrict__ Wp,
    const float* __restrict__ aWhh, const float* __restrict__ W1bp,
    const float* __restrict__ bihEff, const float* __restrict__ abhh,
    float* cp, const float* hpartPriv, __half* h0wT, float* hid,
    float (&htmp)[2][64], int wv, int lane)
{
    float acc[10] = {};
    {   // x segment (k=256)
        const float* w8[8];
#pragma unroll
        for (int r = 0; r < 8; ++r)
            w8[r] = aWih + (size_t)((r >> 1) * HID + i0 + (r & 1)) * (EMB + HID);
        segScanT<2, 8, false>(sm.c.As, xT, w8, acc, wv, lane);
    }
    {   // chat segment (folded ctx weights) + fused W1bp rows
        const float* w10[10];
#pragma unroll
        for (int r = 0; r < 8; ++r)
            w10[r] = Wp + (size_t)((r >> 1) * HID + i0 + (r & 1)) * HID;
        w10[8] = W1bp + (size_t)i0 * HID;
        w10[9] = W1bp + (size_t)(i0 + 1) * HID;
        segScanT<4, 10, true>(sm.c.As, chatT, w10, acc, wv, lane);
    }
    {   // recurrent h segment
        const float* w8[8];
#pragma unroll
        for (int r = 0; r < 8; ++r)
            w8[r] = aWhh + (size_t)((r >> 1) * HID + i0 + (r & 1)) * HID;
        segScanT<4, 8, true>(sm.c.As, h0rT, w8, acc, wv, lane);
    }
#pragma unroll
    for (int r = 0; r < 10; ++r) sm.c.red[wv][r][lane] = acc[r];
    __syncthreads();
    const int t = threadIdx.x;
    if (t < 128) {
        const int b = t & 63, hl = t >> 6;
        float gs[4];
#pragma unroll
        for (int g = 0; g < 4; ++g) {
            const int row = g * HID + i0 + hl;
            float s = bihEff[row] + abhh[row];
#pragma unroll
            for (int w = 0; w < 8; ++w) s += sm.c.red[w][g * 2 + hl][b];
            gs[g] = s;
        }
        const float ig = 1.f / (1.f + __expf(-gs[0]));
        const float fg = 1.f / (1.f + __expf(-gs[1]));
        const float gg = tanhf(gs[2]);
        const float og = 1.f / (1.f + __expf(-gs[3]));
        const float c2 = fg * cp[hl * 64 + b] + ig * gg;
        cp[hl * 64 + b] = c2;
        htmp[hl][b] = og * tanhf(c2);
    } else if (t < 256) {
        const int b = t & 63, hl = (t >> 6) - 2;
        float s = hpartPriv[hl * 64 + b];
#pragma unroll
        for (int w = 0; w < 8; ++w) s += sm.c.red[w][8 + hl][b];
        vst1(hid + (size_t)b * HID + i0 + hl, fmaxf(s, 0.f));
    }
    __syncthreads();
    packRows(h0wT, i0, htmp);
}

// phases B, C: plain rnn LSTM cell
__device__ __forceinline__ void phaseR(SMem& sm, int i0,
    const __half* inT, const __half* recT,
    const float* __restrict__ Wih, const float* __restrict__ Whh,
    const float* __restrict__ bih, const float* __restrict__ bhh,
    float* cp, __half* hOutT, float (&htmp)[2][64], int wv, int lane)
{
    float acc[8] = {};
    {
        const float* w8[8];
#pragma unroll
        for (int r = 0; r < 8; ++r)
            w8[r] = Wih + (size_t)((r >> 1) * HID + i0 + (r & 1)) * HID;
        segScanT<4, 8, true>(sm.c.As, inT, w8, acc, wv, lane);
    }
    {
        const float* w8[8];
#pragma unroll
        for (int r = 0; r < 8; ++r)
            w8[r] = Whh + (size_t)((r >> 1) * HID + i0 + (r & 1)) * HID;
        segScanT<4, 8, true>(sm.c.As, recT, w8, acc, wv, lane);
    }
#pragma unroll
    for (int r = 0; r < 8; ++r) sm.c.red[wv][r][lane] = acc[r];
    __syncthreads();
    const int t = threadIdx.x;
    if (t < 128) {
        const int b = t & 63, hl = t >> 6;
        float gs[4];
#pragma unroll
        for (int g = 0; g < 4; ++g) {
            const int row = g * HID + i0 + hl;
            float s = bih[row] + bhh[row];
#pragma unroll
            for (int w = 0; w < 8; ++w) s += sm.c.red[w][g * 2 + hl][b];
            gs[g] = s;
        }
        const float ig = 1.f / (1.f + __expf(-gs[0]));
        const float fg = 1.f / (1.f + __expf(-gs[1]));
        const float gg = tanhf(gs[2]);
        const float og = 1.f / (1.f + __expf(-gs[3]));
        const float c2 = fg * cp[hl * 64 + b] + ig * gg;
        cp[hl * 64 + b] = c2;
        htmp[hl][b] = og * tanhf(c2);
    }
    __syncthreads();
    packRows(hOutT, i0, htmp);
}

// logits for one step (block -> (b, 16 v's))
__device__ __forceinline__ void logitsPhase(SMem& sm, int bid,
    const float* hid, const float* __restrict__ W2,
    const float* __restrict__ b2, float* __restrict__ out, int tstep)
{
    const int t  = threadIdx.x;
    const int b  = bid & 63;
    const int vg = bid >> 6;
    const int vp = t >> 5;
    const int kk = t & 31;
    float hreg[16];
    const float* hp = hid + (size_t)b * HID + kk * 16;
#pragma unroll
    for (int k = 0; k < 16; ++k) hreg[k] = vld1(hp + k);
    const float* w = W2 + (size_t)(vg * 16 + vp) * HID + kk * 16;
    float s = 0.f;
#pragma unroll
    for (int k = 0; k < 16; ++k) s += hreg[k] * w[k];
    __syncthreads();
    sm.lg.red[vp * 33 + kk] = s;
    __syncthreads();
    if (t < 16) {
        float acc = b2[vg * 16 + t];
#pragma unroll
        for (int k = 0; k < 32; ++k) acc += sm.lg.red[t * 33 + k];
        out[((size_t)b * SLEN + tstep) * VOCAB + vg * 16 + t] = acc;
    }
}

// phase D: dual GEMV (u -> global f32, hpart -> LDS)
__device__ __forceinline__ void phaseD(SMem& sm, int i0,
    const __half* prevT, const float* __restrict__ Pm,
    const float* __restrict__ p0v, const float* __restrict__ W1,
    const float* __restrict__ b1eff, float* u, float* hpartPriv,
    int wv, int lane)
{
    float acc[4] = {};
    const float* w4[4];
    w4[0] = Pm + (size_t)i0 * HID;
    w4[1] = Pm + (size_t)(i0 + 1) * HID;
    w4[2] = W1 + (size_t)i0 * (2 * HID);
    w4[3] = W1 + (size_t)(i0 + 1) * (2 * HID);
    segScanT<4, 4, true>(sm.c.As, prevT, w4, acc, wv, lane);
#pragma unroll
    for (int r = 0; r < 4; ++r) sm.c.red[wv][r][lane] = acc[r];
    __syncthreads();
    const int t = threadIdx.x;
    if (t < 256) {
        const int b = t & 63, r = t >> 6;
        float s = 0.f;
#pragma unroll
        for (int w = 0; w < 8; ++w) s += sm.c.red[w][r][b];
        if (r < 2) vst1(u + (size_t)b * HID + i0 + r, s + p0v[i0 + r]);
        else       hpartPriv[(r - 2) * 64 + b] = s + b1eff[i0 + r - 2];
    }
}

// phase E: attention partials (4 chunks x 64 b, f16 LDS-staged)
__device__ __forceinline__ void phaseE(SMem& sm, int bid,
    const float* u, const __half* __restrict__ enc16,
    float* pm, float* ps, float* pv)
{
    const int t    = threadIdx.x;
    const int b    = bid >> 2;
    const int ch   = bid & 3;
    const int half = t >> 8;
    const int col  = t & 255;
    const int le   = t & 31;
    const int seg  = t >> 5;
    const int sq   = t & 15;
    const int sl   = (t >> 4) & 31;

    sm.a.u_s[t] = vld1(u + (size_t)b * HID + t);
    if (t == 0) { sm.a.msh[0] = -3.0e38f; sm.a.msh[1] = 0.f; sm.a.msh[2] = 0.f; }
    float vx = 0.f, vy = 0.f;

    const uint4* src = reinterpret_cast<const uint4*>(enc16 + ((size_t)b * LLEN + ch * 256) * HID);
    uint4 R[4];
#pragma unroll
    for (int p = 0; p < 4; ++p) R[p] = src[(size_t)sl * 64 + p * 16 + sq];
    __syncthreads();

    for (int blk = 0; blk < 8; ++blk) {
        {
            unsigned* dst = &sm.a.enc[sl * 261];
#pragma unroll
            for (int p = 0; p < 4; ++p) {
                const int c4 = (p * 16 + sq) * 4;
                dst[c4] = R[p].x; dst[c4+1] = R[p].y; dst[c4+2] = R[p].z; dst[c4+3] = R[p].w;
            }
        }
        __syncthreads();
        if (blk < 7) {
#pragma unroll
            for (int p = 0; p < 4; ++p)
                R[p] = src[((size_t)(blk + 1) * 32 + sl) * 64 + p * 16 + sq];
        }
        {   // scores
            float eacc = 0.f;
            const unsigned* er = &sm.a.enc[le * 261];
            const float* us = sm.a.u_s;
#pragma unroll
            for (int uu = 0; uu < 16; ++uu) {
                const int uo = seg * 16 + uu;
                unsigned uw = er[uo];
                float2 f2 = __half22float2(*reinterpret_cast<const __half2*>(&uw));
                eacc += us[2 * uo] * f2.x + us[2 * uo + 1] * f2.y;
            }
            sm.a.accs[seg][le] = eacc;
        }
        __syncthreads();
        if (t < 32) {
            float e = 0.f;
#pragma unroll
            for (int s2 = 0; s2 < 16; ++s2) e += sm.a.accs[s2][t];
            float bm = e;
#pragma unroll
            for (int off = 16; off > 0; off >>= 1) bm = fmaxf(bm, __shfl_xor(bm, off));
            const float m_old = sm.a.msh[0];
            const float m_new = fmaxf(m_old, bm);
            const float wl = __expf(e - m_new);
            float sw = wl;
#pragma unroll
            for (int off = 16; off > 0; off >>= 1) sw += __shfl_xor(sw, off);
            sm.a.w_s[t] = wl;
            if (t == 0) {
                const float sc = __expf(m_old - m_new);
                sm.a.msh[2] = sc;
                sm.a.msh[1] = sm.a.msh[1] * sc + sw;
                sm.a.msh[0] = m_new;
            }
        }
        __syncthreads();
        {
            const float sc = sm.a.msh[2];
            vx *= sc; vy *= sc;
#pragma unroll
            for (int ll = 0; ll < 16; ++ll) {
                const int l = half * 16 + ll;
                const float wl = sm.a.w_s[l];
                unsigned uw = sm.a.enc[l * 261 + col];
                float2 f2 = __half22float2(*reinterpret_cast<const __half2*>(&uw));
                vx += wl * f2.x; vy += wl * f2.y;
            }
        }
        __syncthreads();
    }
    if (half == 1) { sm.a.u_s[2 * col] = vx; sm.a.u_s[2 * col + 1] = vy; }
    __syncthreads();
    if (half == 0) {
        vx += sm.a.u_s[2 * col];
        vy += sm.a.u_s[2 * col + 1];
        const int pc = b * 4 + ch;
        vst1(pv + (size_t)pc * HID + 2 * col,     vx);
        vst1(pv + (size_t)pc * HID + 2 * col + 1, vy);
        if (t == 0) { vst1(pm + pc, sm.a.msh[0]); vst1(ps + pc, sm.a.msh[1]); }
    }
}

// phase F: combine partials -> normalized chat, write transposed f16 rows
__device__ __forceinline__ void phaseF(int bid,
    const float* pm, const float* ps, const float* pv, __half* chatT)
{
    const int t = threadIdx.x;
    if (t < 128) {
        const int b = t & 63;
        const int j = bid * 2 + (t >> 6);
        float m[4], sd[4], pvv[4];
#pragma unroll
        for (int c = 0; c < 4; ++c) m[c]   = vld1(pm + b * 4 + c);
#pragma unroll
        for (int c = 0; c < 4; ++c) sd[c]  = vld1(ps + b * 4 + c);
#pragma unroll
        for (int c = 0; c < 4; ++c) pvv[c] = vld1(pv + (size_t)(b * 4 + c) * HID + j);
        float M = fmaxf(fmaxf(m[0], m[1]), fmaxf(m[2], m[3]));
        float den = 0.f, num = 0.f;
#pragma unroll
        for (int c = 0; c < 4; ++c) {
            float e = __expf(m[c] - M);
            den += e * sd[c]; num += e * pvv[c];
        }
        float v = num / den;
        float vn = __shfl_down(v, 1);
        if ((b & 1) == 0)
            vstu(reinterpret_cast<unsigned*>(chatT) + (size_t)j * 32 + (b >> 1),
                 packh2(v, vn));
    }
}

// tail: hid(S-1) = relu(hpart + W1bp@chat)
__device__ __forceinline__ void phaseT(SMem& sm, int i0,
    const __half* chatT, const float* __restrict__ W1bp,
    const float* hpartPriv, float* hid, int wv, int lane)
{
    float acc[2] = {};
    const float* w2[2];
    w2[0] = W1bp + (size_t)i0 * HID;
    w2[1] = W1bp + (size_t)(i0 + 1) * HID;
    segScanT<4, 2, true>(sm.c.As, chatT, w2, acc, wv, lane);
    sm.c.red[wv][0][lane] = acc[0];
    sm.c.red[wv][1][lane] = acc[1];
    __syncthreads();
    const int t = threadIdx.x;
    if (t < 128) {
        const int b = t & 63, r = t >> 6;
        float s = hpartPriv[r * 64 + b];
#pragma unroll
        for (int w = 0; w < 8; ++w) s += sm.c.red[w][r][b];
        vst1(hid + (size_t)b * HID + i0 + r, fmaxf(s, 0.f));
    }
}

// ---------------------------------------------------------------------------
__global__ __launch_bounds__(NT, 1)
void k_seq(const __half* __restrict__ xemb16, const __half* __restrict__ enc16,
           const float* __restrict__ aWih, const float* __restrict__ aWhh,
           const float* __restrict__ bihEff, const float* __restrict__ abhh,
           const float* __restrict__ rWih, const float* __restrict__ rWhh,
           const float* __restrict__ rbih, const float* __restrict__ rbhh,
           const float* __restrict__ Pm, const float* __restrict__ p0v,
           const float* __restrict__ W1, const float* __restrict__ b1eff,
           const float* __restrict__ Wp, const float* __restrict__ W1bp,
           const float* __restrict__ W2, const float* __restrict__ b2,
           __half* h0T, __half* hs0T, __half* hs1T, __half* chatT,
           float* u, float* hid, float* pv, float* pm, float* ps,
           float* out, unsigned* bar)
{
    __shared__ SMem sm;
    __shared__ float cPriv[3][128];
    __shared__ float hpartPriv[128];
    __shared__ float htmp[2][64];

    const int bid  = blockIdx.x;
    const int i0   = bid * 2;
    const int t0   = threadIdx.x;
    const int wv   = __builtin_amdgcn_readfirstlane(t0 >> 6);
    const int lane = t0 & 63;
    if (t0 < 128) { cPriv[0][t0] = 0.f; cPriv[1][t0] = 0.f; cPriv[2][t0] = 0.f;
                    hpartPriv[t0] = 0.f; }
    __syncthreads();

    unsigned nb = 0;
    for (int t = 0; t < SLEN; ++t) {
        const int par = t & 1;
        const __half* h0r  = h0T  + (size_t)par * 32768;
        __half*       h0w  = h0T  + (size_t)(par ^ 1) * 32768;
        const __half* hs0r = hs0T + (size_t)par * 32768;
        __half*       hs0w = hs0T + (size_t)(par ^ 1) * 32768;
        const __half* hs1r = hs1T + (size_t)par * 32768;
        __half*       hs1w = hs1T + (size_t)(par ^ 1) * 32768;

        phaseA(sm, i0, xemb16 + (size_t)t * BS * EMB, chatT, h0r,
               aWih, Wp, aWhh, W1bp, bihEff, abhh,
               cPriv[0], hpartPriv, h0w, hid, htmp, wv, lane);
        gridbar(bar, ++nb);
        phaseR(sm, i0, h0w, hs0r, rWih, rWhh, rbih, rbhh,
               cPriv[1], hs0w, htmp, wv, lane);
        gridbar(bar, ++nb);
        phaseR(sm, i0, hs0w, hs1r, rWih + (size_t)G4 * HID, rWhh + (size_t)G4 * HID,
               rbih + G4, rbhh + G4, cPriv[2], hs1w, htmp, wv, lane);
        gridbar(bar, ++nb);
        if (t > 0) logitsPhase(sm, bid, hid, W2, b2, out, t - 1);
        phaseD(sm, i0, hs1w, Pm, p0v, W1, b1eff, u, hpartPriv, wv, lane);
        gridbar(bar, ++nb);
        phaseE(sm, bid, u, enc16, pm, ps, pv);
        gridbar(bar, ++nb);
        phaseF(bid, pm, ps, pv, chatT);
        gridbar(bar, ++nb);
    }
    phaseT(sm, i0, chatT, W1bp, hpartPriv, hid, wv, lane);
    gridbar(bar, ++nb);
    logitsPhase(sm, bid, hid, W2, b2, out, SLEN - 1);
}

// ---------------------------------------------------------------------------
extern "C" void kernel_launch(void* const* d_in, const int* in_sizes, int n_in,
                              void* d_out, int out_size, void* d_ws, size_t ws_size,
                              hipStream_t stream)
{
    const int*   y    = (const int*)  d_in[0];
    const float* enc  = (const float*)d_in[1];
    const float* emb  = (const float*)d_in[2];
    const float* aWih = (const float*)d_in[3];
    const float* aWhh = (const float*)d_in[4];
    const float* abih = (const float*)d_in[5];
    const float* abhh = (const float*)d_in[6];
    const float* rWih = (const float*)d_in[7];
    const float* rWhh = (const float*)d_in[8];
    const float* rbih = (const float*)d_in[9];
    const float* rbhh = (const float*)d_in[10];
    const float* Wsw  = (const float*)d_in[11];
    const float* Wsb  = (const float*)d_in[12];
    const float* Whw  = (const float*)d_in[13];
    const float* Whb  = (const float*)d_in[14];
    const float* W1   = (const float*)d_in[15];
    const float* b1   = (const float*)d_in[16];
    const float* W2   = (const float*)d_in[17];
    const float* b2   = (const float*)d_in[18];
    float* out = (float*)d_out;

    char* base = (char*)d_ws;
    unsigned* bar = (unsigned*)base;                 base += 4096;
    // zero region (f16 transposed state): h0(2), hs0(2), hs1(2), chat = 448KB
    __half* h0T   = (__half*)base;                   base += 2 * 65536;
    __half* hs0T  = (__half*)base;                   base += 2 * 65536;
    __half* hs1T  = (__half*)base;                   base += 2 * 65536;
    __half* chatT = (__half*)base;                   base += 65536;
    size_t zeroBytes = (size_t)(base - (char*)h0T);
    float* u      = (float*)base;                    base += 131072;
    float* hid    = (float*)base;                    base += 131072;
    float* pv     = (float*)base;                    base += 524288;
    float* pm     = (float*)base;                    base += 1024;
    float* ps     = (float*)base;                    base += 1024;
    float* Pm     = (float*)base;                    base += 1048576;
    float* p0v    = (float*)base;                    base += 2048;
    float* Wp     = (float*)base;                    base += (size_t)G4 * HID * 4;
    float* W1bp   = (float*)base;                    base += (size_t)HID * HID * 4;
    float* bihEff = (float*)base;                    base += 8192;
    float* b1eff  = (float*)base;                    base += 2048;
    __half* xemb16 = (__half*)base;                  base += (size_t)SLEN * BS * EMB * 2;
    __half* enc16  = (__half*)base;                  base += (size_t)BS * LLEN * HID * 2;
    size_t need = (size_t)(base - (char*)d_ws);
    if (ws_size < need) return;   // loud failure (output stays zero)

    hipMemsetAsync(bar, 0, 4096, stream);
    hipMemsetAsync(h0T, 0, zeroBytes, stream);

    k_embed16T<<<(SLEN * BS * EMB) / 256, 256, 0, stream>>>(y, emb, xemb16);
    k_cast<<<4096, 256, 0, stream>>>(enc, enc16, (BS * LLEN * HID) / 4);
    k_pmat<<<HID, 256, 0, stream>>>(Whw, Wsw, Wsb, Pm, p0v);
    k_fold<<<G4 + HID, 256, 0, stream>>>(aWih, W1, Whw, Whb, abih, b1,
                                         Wp, W1bp, bihEff, b1eff);

    k_seq<<<NB, NT, 0, stream>>>(xemb16, enc16,
        aWih, aWhh, bihEff, abhh, rWih, rWhh, rbih, rbhh,
        Pm, p0v, W1, b1eff, Wp, W1bp, W2, b2,
        h0T, hs0T, hs1T, chatT, u, hid, pv, pm, ps, out, bar);
}

// Round 10
// 17706.345 us; speedup vs baseline: 2.3549x; 1.0533x over previous
//
#include <hip/hip_runtime.h>
#include <hip/hip_fp16.h>

#define HID   512
#define EMB   256
#define VOCAB 64
#define BS    64
#define SLEN  128
#define LLEN  1024
#define G4    2048
#define NB    256
#define NT    1024
#define NW    16          // waves per block
#define ASTR  66          // unpacked-tile row stride (f32): 2-way banks
#define ASZ   (128 * ASTR)

typedef unsigned u32x4 __attribute__((ext_vector_type(4)));

// ---------------------------------------------------------------------------
// MALL-coherent (cache-bypass) access helpers — proven R5-R9 protocol
__device__ __forceinline__ u32x4 vldq(const unsigned* p) {
    return *reinterpret_cast<const volatile u32x4*>(p);
}
__device__ __forceinline__ float vld1(const float* p) {
    return *reinterpret_cast<const volatile float*>(p);
}
__device__ __forceinline__ void vst1(float* p, float v) {
    *reinterpret_cast<volatile float*>(p) = v;
}
__device__ __forceinline__ void vstu(unsigned* p, unsigned v) {
    *reinterpret_cast<volatile unsigned*>(p) = v;
}
__device__ __forceinline__ unsigned packh2(float x, float y) {
    __half2 h = __floats2half2_rn(x, y);
    return *reinterpret_cast<unsigned*>(&h);
}

// ---------------------------------------------------------------------------
struct SCell { float As[2 * ASZ]; float red[NW][10][66]; };
struct SAttn { float u_s[512]; float w_s[32]; float msh[4];
               float accs[32][34]; float vred[4][512]; unsigned enc[32 * 261]; };
struct SLog  { float red[16 * 65]; };
union SMem { SCell c; SAttn a; SLog lg; };

// ---------------------------------------------------------------------------
// grid barrier v5: flat slot array (no RMW); wave0 polls all 256 slots.
__device__ __forceinline__ void gridbar(unsigned* bar, unsigned nb)
{
    __syncthreads();
    const int t = threadIdx.x;
    if (t < 64) {
        if (t == 0)
            __hip_atomic_store(bar + blockIdx.x, nb, __ATOMIC_RELAXED,
                               __HIP_MEMORY_SCOPE_AGENT);
        for (;;) {
            bool ok = true;
#pragma unroll
            for (int i = 0; i < 4; ++i) {
                unsigned v = __hip_atomic_load(bar + i * 64 + t, __ATOMIC_RELAXED,
                                               __HIP_MEMORY_SCOPE_AGENT);
                ok &= (v >= nb);
            }
            if (__all((int)ok)) break;
            __builtin_amdgcn_s_sleep(1);
        }
    }
    __syncthreads();
}

// ---------------------------------------------------------------------------
// one-time kernels
__global__ __launch_bounds__(256)
void k_embed16T(const int* __restrict__ y, const float* __restrict__ emb,
                __half* __restrict__ xemb16)   // [t][e][b] f16
{
    int i = blockIdx.x * 256 + threadIdx.x;
    int b  = i & 63;
    int e  = (i >> 6) & 255;
    int ts = i >> 14;
    xemb16[i] = __float2half(emb[y[b * SLEN + ts] * EMB + e]);
}

__global__ __launch_bounds__(256)
void k_cast(const float* __restrict__ src, __half* __restrict__ dst, int n4)
{
    int i = blockIdx.x * 256 + threadIdx.x;
    int stride = gridDim.x * 256;
    for (; i < n4; i += stride) {
        float4 v = reinterpret_cast<const float4*>(src)[i];
        reinterpret_cast<__half2*>(dst)[2 * i]     = __floats2half2_rn(v.x, v.y);
        reinterpret_cast<__half2*>(dst)[2 * i + 1] = __floats2half2_rn(v.z, v.w);
    }
}

__global__ __launch_bounds__(256)
void k_pmat(const float* __restrict__ Whw, const float* __restrict__ Wsw,
            const float* __restrict__ Wsb, float* __restrict__ P,
            float* __restrict__ p0)
{
    const int i = blockIdx.x;
    const int t = threadIdx.x;
    float a0 = 0.f, a1 = 0.f, ap = 0.f;
    for (int h = 0; h < HID; ++h) {
        float whi = Whw[h * HID + i];
        a0 += whi * Wsw[h * HID + t];
        a1 += whi * Wsw[h * HID + t + 256];
        ap += whi * Wsb[h];
    }
    P[i * HID + t]       = a0;
    P[i * HID + t + 256] = a1;
    if (t == 0) p0[i] = ap;
}

// fold ctx=Whw@chat+Whb into consumers (exact algebra, proven R7/R8)
__global__ __launch_bounds__(256)
void k_fold(const float* __restrict__ aWih, const float* __restrict__ W1,
            const float* __restrict__ Whw, const float* __restrict__ Whb,
            const float* __restrict__ abih, const float* __restrict__ b1,
            float* __restrict__ Wp, float* __restrict__ W1bp,
            float* __restrict__ bihEff, float* __restrict__ b1eff)
{
    const int r = blockIdx.x;
    const int t = threadIdx.x;
    __shared__ float ssrc[512];
    const float* src;
    float* dst;
    if (r < G4) { src = aWih + (size_t)r * (EMB + HID) + EMB; dst = Wp + (size_t)r * HID; }
    else        { src = W1 + (size_t)(r - G4) * (2 * HID) + HID; dst = W1bp + (size_t)(r - G4) * HID; }
    ssrc[t]       = src[t];
    ssrc[t + 256] = src[t + 256];
    __syncthreads();
    float a0 = 0.f, a1 = 0.f;
    for (int h = 0; h < HID; ++h) {
        const float s = ssrc[h];
        a0 += s * Whw[h * HID + t];
        a1 += s * Whw[h * HID + t + 256];
    }
    dst[t]       = a0;
    dst[t + 256] = a1;
    if (t == 0) {
        float bb = 0.f;
        for (int h = 0; h < HID; ++h) bb += ssrc[h] * Whb[h];
        if (r < G4) bihEff[r] = abih[r] + bb;
        else        b1eff[r - G4] = b1[r - G4] + bb;
    }
}

// ---------------------------------------------------------------------------
// staged transposed-f16 scan: activation A is [NTILES*128 k][64 b] f16.
// Waves 0-7 stage (proven 2-way bank pattern); all 16 waves compute
// (8 k per wave per tile). Double-buffered, 1 sync/tile.
template<int NTILES, int NR, bool VOL>
__device__ __forceinline__ void segScanT(float* As, const __half* A,
    const float* const* w, float* acc, int wv, int lane)
{
    const int t = threadIdx.x;
    const bool st = (t < 512);
    const unsigned* ga = reinterpret_cast<const unsigned*>(A) + (size_t)(t & 511) * 8;
    const int kRow = (t & 511) >> 2;
    const int c0   = (t & 3) * 16;
    u32x4 Ra[2], Rb[2];

#define LOADT(R, j) do { const unsigned* _p = ga + (size_t)(j) * 4096;            \
        if (VOL) { R[0] = vldq(_p); R[1] = vldq(_p + 4); }                        \
        else { R[0] = *reinterpret_cast<const u32x4*>(_p);                        \
               R[1] = *reinterpret_cast<const u32x4*>(_p + 4); } } while (0)

    if (st) LOADT(Ra, 0);
    __syncthreads();                      // handoff: prior users of As done
#pragma unroll
    for (int j = 0; j < NTILES; ++j) {
        if (st) {
            float2* dst = reinterpret_cast<float2*>(As + (j & 1) * ASZ + kRow * ASTR + c0);
            const u32x4* R = (j & 1) ? Rb : Ra;
#pragma unroll
            for (int q = 0; q < 2; ++q)
#pragma unroll
                for (int h = 0; h < 4; ++h) {
                    unsigned uw = R[q][h];
                    dst[q * 4 + h] = __half22float2(*reinterpret_cast<const __half2*>(&uw));
                }
            if (j + 1 < NTILES) { if (j & 1) { LOADT(Ra, j + 1); } else { LOADT(Rb, j + 1); } }
        }
        __syncthreads();
        const float* as = As + (j & 1) * ASZ + (wv * 8) * ASTR + lane;
#pragma unroll
        for (int kk = 0; kk < 8; ++kk) {
            const float a = as[kk * ASTR];
            const int k = j * 128 + wv * 8 + kk;
#pragma unroll
            for (int r = 0; r < NR; ++r)
                acc[r] += a * w[r][k];
        }
    }
#undef LOADT
}

// coalesced h-state pack-write: rows i0,i0+1 of [k][b] f16 = 64 u32 burst
__device__ __forceinline__ void packRows(__half* dstH, int i0, const float (&htmp)[2][64])
{
    const int t = threadIdx.x;
    if (t < 64) {
        const int hl = t >> 5;
        const int b2 = (t & 31) * 2;
        vstu(reinterpret_cast<unsigned*>(dstH) + (size_t)(i0 + hl) * 32 + (t & 31),
             packh2(htmp[hl][b2], htmp[hl][b2 + 1]));
    }
}

// ---------------------------------------------------------------------------
// phase A: attention-input LSTM cell + fused hid(t-1) finish
__device__ __forceinline__ void phaseA(SMem& sm, int i0,
    const __half* xT, const __half* chatT, const __half* h0rT,
    const float* __restrict__ aWih, const float* __restrict__ Wp,
    const float* __restrict__ aWhh, const float* __restrict__ W1bp,
    const float* __restrict__ bihEff, const float* __restrict__ abhh,
    float* cp, const float* hpartPriv, __half* h0wT, float* hid,
    float (&htmp)[2][64], int wv, int lane)
{
    float acc[10] = {};
    {   // x segment (k=256)
        const float* w8[8];
#pragma unroll
        for (int r = 0; r < 8; ++r)
            w8[r] = aWih + (size_t)((r >> 1) * HID + i0 + (r & 1)) * (EMB + HID);
        segScanT<2, 8, false>(sm.c.As, xT, w8, acc, wv, lane);
    }
    {   // chat segment (folded ctx weights) + fused W1bp rows
        const float* w10[10];
#pragma unroll
        for (int r = 0; r < 8; ++r)
            w10[r] = Wp + (size_t)((r >> 1) * HID + i0 + (r & 1)) * HID;
        w10[8] = W1bp + (size_t)i0 * HID;
        w10[9] = W1bp + (size_t)(i0 + 1) * HID;
        segScanT<4, 10, true>(sm.c.As, chatT, w10, acc, wv, lane);
    }
    {   // recurrent h segment
        const float* w8[8];
#pragma unroll
        for (int r = 0; r < 8; ++r)
            w8[r] = aWhh + (size_t)((r >> 1) * HID + i0 + (r & 1)) * HID;
        segScanT<4, 8, true>(sm.c.As, h0rT, w8, acc, wv, lane);
    }
#pragma unroll
    for (int r = 0; r < 10; ++r) sm.c.red[wv][r][lane] = acc[r];
    __syncthreads();
    const int t = threadIdx.x;
    if (t < 128) {
        const int b = t & 63, hl = t >> 6;
        float gs[4];
#pragma unroll
        for (int g = 0; g < 4; ++g) {
            const int row = g * HID + i0 + hl;
            float s = bihEff[row] + abhh[row];
#pragma unroll
            for (int w = 0; w < NW; ++w) s += sm.c.red[w][g * 2 + hl][b];
            gs[g] = s;
        }
        const float ig = 1.f / (1.f + __expf(-gs[0]));
        const float fg = 1.f / (1.f + __expf(-gs[1]));
        const float gg = tanhf(gs[2]);
        const float og = 1.f / (1.f + __expf(-gs[3]));
        const float c2 = fg * cp[hl * 64 + b] + ig * gg;
        cp[hl * 64 + b] = c2;
        htmp[hl][b] = og * tanhf(c2);
    } else if (t < 256) {
        const int b = t & 63, hl = (t >> 6) - 2;
        float s = hpartPriv[hl * 64 + b];
#pragma unroll
        for (int w = 0; w < NW; ++w) s += sm.c.red[w][8 + hl][b];
        vst1(hid + (size_t)b * HID + i0 + hl, fmaxf(s, 0.f));
    }
    __syncthreads();
    packRows(h0wT, i0, htmp);
}

// phases B, C: plain rnn LSTM cell
__device__ __forceinline__ void phaseR(SMem& sm, int i0,
    const __half* inT, const __half* recT,
    const float* __restrict__ Wih, const float* __restrict__ Whh,
    const float* __restrict__ bih, const float* __restrict__ bhh,
    float* cp, __half* hOutT, float (&htmp)[2][64], int wv, int lane)
{
    float acc[8] = {};
    {
        const float* w8[8];
#pragma unroll
        for (int r = 0; r < 8; ++r)
            w8[r] = Wih + (size_t)((r >> 1) * HID + i0 + (r & 1)) * HID;
        segScanT<4, 8, true>(sm.c.As, inT, w8, acc, wv, lane);
    }
    {
        const float* w8[8];
#pragma unroll
        for (int r = 0; r < 8; ++r)
            w8[r] = Whh + (size_t)((r >> 1) * HID + i0 + (r & 1)) * HID;
        segScanT<4, 8, true>(sm.c.As, recT, w8, acc, wv, lane);
    }
#pragma unroll
    for (int r = 0; r < 8; ++r) sm.c.red[wv][r][lane] = acc[r];
    __syncthreads();
    const int t = threadIdx.x;
    if (t < 128) {
        const int b = t & 63, hl = t >> 6;
        float gs[4];
#pragma unroll
        for (int g = 0; g < 4; ++g) {
            const int row = g * HID + i0 + hl;
            float s = bih[row] + bhh[row];
#pragma unroll
            for (int w = 0; w < NW; ++w) s += sm.c.red[w][g * 2 + hl][b];
            gs[g] = s;
        }
        const float ig = 1.f / (1.f + __expf(-gs[0]));
        const float fg = 1.f / (1.f + __expf(-gs[1]));
        const float gg = tanhf(gs[2]);
        const float og = 1.f / (1.f + __expf(-gs[3]));
        const float c2 = fg * cp[hl * 64 + b] + ig * gg;
        cp[hl * 64 + b] = c2;
        htmp[hl][b] = og * tanhf(c2);
    }
    __syncthreads();
    packRows(hOutT, i0, htmp);
}

// logits for one step (block -> (b, 16 v's)); 1024-thread mapping
__device__ __forceinline__ void logitsPhase(SMem& sm, int bid,
    const float* hid, const float* __restrict__ W2,
    const float* __restrict__ b2, float* __restrict__ out, int tstep)
{
    const int t  = threadIdx.x;
    const int b  = bid & 63;
    const int vg = bid >> 6;
    const int vp = t >> 6;        // 0..15
    const int kk = t & 63;        // 0..63
    float hreg[8];
    const float* hp = hid + (size_t)b * HID + kk * 8;
#pragma unroll
    for (int k = 0; k < 8; ++k) hreg[k] = vld1(hp + k);
    const float* w = W2 + (size_t)(vg * 16 + vp) * HID + kk * 8;
    float s = 0.f;
#pragma unroll
    for (int k = 0; k < 8; ++k) s += hreg[k] * w[k];
    __syncthreads();
    sm.lg.red[vp * 65 + kk] = s;
    __syncthreads();
    if (t < 16) {
        float acc = b2[vg * 16 + t];
#pragma unroll
        for (int k = 0; k < 64; ++k) acc += sm.lg.red[t * 65 + k];
        out[((size_t)b * SLEN + tstep) * VOCAB + vg * 16 + t] = acc;
    }
}

// phase D: dual GEMV (u -> global f32, hpart -> LDS)
__device__ __forceinline__ void phaseD(SMem& sm, int i0,
    const __half* prevT, const float* __restrict__ Pm,
    const float* __restrict__ p0v, const float* __restrict__ W1,
    const float* __restrict__ b1eff, float* u, float* hpartPriv,
    int wv, int lane)
{
    float acc[4] = {};
    const float* w4[4];
    w4[0] = Pm + (size_t)i0 * HID;
    w4[1] = Pm + (size_t)(i0 + 1) * HID;
    w4[2] = W1 + (size_t)i0 * (2 * HID);
    w4[3] = W1 + (size_t)(i0 + 1) * (2 * HID);
    segScanT<4, 4, true>(sm.c.As, prevT, w4, acc, wv, lane);
#pragma unroll
    for (int r = 0; r < 4; ++r) sm.c.red[wv][r][lane] = acc[r];
    __syncthreads();
    const int t = threadIdx.x;
    if (t < 256) {
        const int b = t & 63, r = t >> 6;
        float s = 0.f;
#pragma unroll
        for (int w = 0; w < NW; ++w) s += sm.c.red[w][r][b];
        if (r < 2) vst1(u + (size_t)b * HID + i0 + r, s + p0v[i0 + r]);
        else       hpartPriv[(r - 2) * 64 + b] = s + b1eff[i0 + r - 2];
    }
}

// phase E: attention partials (4 chunks x 64 b), 1024-thread mapping
__device__ __forceinline__ void phaseE(SMem& sm, int bid,
    const float* u, const __half* __restrict__ enc16,
    float* pm, float* ps, float* pv)
{
    const int t   = threadIdx.x;
    const int b   = bid >> 2;
    const int ch  = bid & 3;
    const int le  = t & 31;
    const int seg = t >> 5;        // 0..31
    const int sq  = t & 15;
    const int sl  = (t >> 4) & 31; // rows for staging (t<512)
    const int rg  = t >> 8;        // 0..3 row-groups for PV
    const int col = t & 255;

    if (t < 512) sm.a.u_s[t] = vld1(u + (size_t)b * HID + t);
    if (t == 0) { sm.a.msh[0] = -3.0e38f; sm.a.msh[1] = 0.f; sm.a.msh[2] = 0.f; }
    float vx = 0.f, vy = 0.f;

    const uint4* src = reinterpret_cast<const uint4*>(enc16 + ((size_t)b * LLEN + ch * 256) * HID);
    uint4 R[4];
    if (t < 512) {
#pragma unroll
        for (int p = 0; p < 4; ++p) R[p] = src[(size_t)sl * 64 + p * 16 + sq];
    }
    __syncthreads();

    for (int blk = 0; blk < 8; ++blk) {
        if (t < 512) {
            unsigned* dst = &sm.a.enc[sl * 261];
#pragma unroll
            for (int p = 0; p < 4; ++p) {
                const int c4 = (p * 16 + sq) * 4;
                dst[c4] = R[p].x; dst[c4+1] = R[p].y; dst[c4+2] = R[p].z; dst[c4+3] = R[p].w;
            }
        }
        __syncthreads();
        if (t < 512 && blk < 7) {
#pragma unroll
            for (int p = 0; p < 4; ++p)
                R[p] = src[((size_t)(blk + 1) * 32 + sl) * 64 + p * 16 + sq];
        }
        {   // scores: 32 segs x 32 rows, 8 half2 per seg
            float eacc = 0.f;
            const unsigned* er = &sm.a.enc[le * 261];
            const float* us = sm.a.u_s;
#pragma unroll
            for (int uu = 0; uu < 8; ++uu) {
                const int uo = seg * 8 + uu;
                unsigned uw = er[uo];
                float2 f2 = __half22float2(*reinterpret_cast<const __half2*>(&uw));
                eacc += us[2 * uo] * f2.x + us[2 * uo + 1] * f2.y;
            }
            sm.a.accs[seg][le] = eacc;
        }
        __syncthreads();
        if (t < 32) {
            float e = 0.f;
#pragma unroll
            for (int s2 = 0; s2 < 32; ++s2) e += sm.a.accs[s2][t];
            float bm = e;
#pragma unroll
            for (int off = 16; off > 0; off >>= 1) bm = fmaxf(bm, __shfl_xor(bm, off));
            const float m_old = sm.a.msh[0];
            const float m_new = fmaxf(m_old, bm);
            const float wl = __expf(e - m_new);
            float sw = wl;
#pragma unroll
            for (int off = 16; off > 0; off >>= 1) sw += __shfl_xor(sw, off);
            sm.a.w_s[t] = wl;
            if (t == 0) {
                const float sc = __expf(m_old - m_new);
                sm.a.msh[2] = sc;
                sm.a.msh[1] = sm.a.msh[1] * sc + sw;
                sm.a.msh[0] = m_new;
            }
        }
        __syncthreads();
        {   // weighted accumulate: 4 row-groups x 8 rows each
            const float sc = sm.a.msh[2];
            vx *= sc; vy *= sc;
#pragma unroll
            for (int ll = 0; ll < 8; ++ll) {
                const int l = rg * 8 + ll;
                const float wl = sm.a.w_s[l];
                unsigned uw = sm.a.enc[l * 261 + col];
                float2 f2 = __half22float2(*reinterpret_cast<const __half2*>(&uw));
                vx += wl * f2.x; vy += wl * f2.y;
            }
        }
        __syncthreads();
    }
    sm.a.vred[rg][2 * col]     = vx;
    sm.a.vred[rg][2 * col + 1] = vy;
    __syncthreads();
    if (t < 512) {
        float v = sm.a.vred[0][t] + sm.a.vred[1][t] + sm.a.vred[2][t] + sm.a.vred[3][t];
        const int pc = b * 4 + ch;
        vst1(pv + (size_t)pc * HID + t, v);
        if (t == 0) { vst1(pm + pc, sm.a.msh[0]); vst1(ps + pc, sm.a.msh[1]); }
    }
}

// phase F: combine partials -> normalized chat, write transposed f16 rows
__device__ __forceinline__ void phaseF(int bid,
    const float* pm, const float* ps, const float* pv, __half* chatT)
{
    const int t = threadIdx.x;
    if (t < 128) {
        const int b = t & 63;
        const int j = bid * 2 + (t >> 6);
        float m[4], sd[4], pvv[4];
#pragma unroll
        for (int c = 0; c < 4; ++c) m[c]   = vld1(pm + b * 4 + c);
#pragma unroll
        for (int c = 0; c < 4; ++c) sd[c]  = vld1(ps + b * 4 + c);
#pragma unroll
        for (int c = 0; c < 4; ++c) pvv[c] = vld1(pv + (size_t)(b * 4 + c) * HID + j);
        float M = fmaxf(fmaxf(m[0], m[1]), fmaxf(m[2], m[3]));
        float den = 0.f, num = 0.f;
#pragma unroll
        for (int c = 0; c < 4; ++c) {
            float e = __expf(m[c] - M);
            den += e * sd[c]; num += e * pvv[c];
        }
        float v = num / den;
        float vn = __shfl_down(v, 1);
        if ((b & 1) == 0)
            vstu(reinterpret_cast<unsigned*>(chatT) + (size_t)j * 32 + (b >> 1),
                 packh2(v, vn));
    }
}

// tail: hid(S-1) = relu(hpart + W1bp@chat)
__device__ __forceinline__ void phaseT(SMem& sm, int i0,
    const __half* chatT, const float* __restrict__ W1bp,
    const float* hpartPriv, float* hid, int wv, int lane)
{
    float acc[2] = {};
    const float* w2[2];
    w2[0] = W1bp + (size_t)i0 * HID;
    w2[1] = W1bp + (size_t)(i0 + 1) * HID;
    segScanT<4, 2, true>(sm.c.As, chatT, w2, acc, wv, lane);
    sm.c.red[wv][0][lane] = acc[0];
    sm.c.red[wv][1][lane] = acc[1];
    __syncthreads();
    const int t = threadIdx.x;
    if (t < 128) {
        const int b = t & 63, r = t >> 6;
        float s = hpartPriv[r * 64 + b];
#pragma unroll
        for (int w = 0; w < NW; ++w) s += sm.c.red[w][r][b];
        vst1(hid + (size_t)b * HID + i0 + r, fmaxf(s, 0.f));
    }
}

// ---------------------------------------------------------------------------
__global__ __launch_bounds__(NT, 1)
void k_seq(const __half* __restrict__ xemb16, const __half* __restrict__ enc16,
           const float* __restrict__ aWih, const float* __restrict__ aWhh,
           const float* __restrict__ bihEff, const float* __restrict__ abhh,
           const float* __restrict__ rWih, const float* __restrict__ rWhh,
           const float* __restrict__ rbih, const float* __restrict__ rbhh,
           const float* __restrict__ Pm, const float* __restrict__ p0v,
           const float* __restrict__ W1, const float* __restrict__ b1eff,
           const float* __restrict__ Wp, const float* __restrict__ W1bp,
           const float* __restrict__ W2, const float* __restrict__ b2,
           __half* h0T, __half* hs0T, __half* hs1T, __half* chatT,
           float* u, float* hid, float* pv, float* pm, float* ps,
           float* out, unsigned* bar)
{
    __shared__ SMem sm;
    __shared__ float cPriv[3][128];
    __shared__ float hpartPriv[128];
    __shared__ float htmp[2][64];

    const int bid  = blockIdx.x;
    const int i0   = bid * 2;
    const int t0   = threadIdx.x;
    const int wv   = __builtin_amdgcn_readfirstlane(t0 >> 6);
    const int lane = t0 & 63;
    if (t0 < 128) { cPriv[0][t0] = 0.f; cPriv[1][t0] = 0.f; cPriv[2][t0] = 0.f;
                    hpartPriv[t0] = 0.f; }
    __syncthreads();

    unsigned nb = 0;
    for (int t = 0; t < SLEN; ++t) {
        const int par = t & 1;
        const __half* h0r  = h0T  + (size_t)par * 32768;
        __half*       h0w  = h0T  + (size_t)(par ^ 1) * 32768;
        const __half* hs0r = hs0T + (size_t)par * 32768;
        __half*       hs0w = hs0T + (size_t)(par ^ 1) * 32768;
        const __half* hs1r = hs1T + (size_t)par * 32768;
        __half*       hs1w = hs1T + (size_t)(par ^ 1) * 32768;

        phaseA(sm, i0, xemb16 + (size_t)t * BS * EMB, chatT, h0r,
               aWih, Wp, aWhh, W1bp, bihEff, abhh,
               cPriv[0], hpartPriv, h0w, hid, htmp, wv, lane);
        gridbar(bar, ++nb);
        phaseR(sm, i0, h0w, hs0r, rWih, rWhh, rbih, rbhh,
               cPriv[1], hs0w, htmp, wv, lane);
        gridbar(bar, ++nb);
        phaseR(sm, i0, hs0w, hs1r, rWih + (size_t)G4 * HID, rWhh + (size_t)G4 * HID,
               rbih + G4, rbhh + G4, cPriv[2], hs1w, htmp, wv, lane);
        gridbar(bar, ++nb);
        if (t > 0) logitsPhase(sm, bid, hid, W2, b2, out, t - 1);
        phaseD(sm, i0, hs1w, Pm, p0v, W1, b1eff, u, hpartPriv, wv, lane);
        gridbar(bar, ++nb);
        phaseE(sm, bid, u, enc16, pm, ps, pv);
        gridbar(bar, ++nb);
        phaseF(bid, pm, ps, pv, chatT);
        gridbar(bar, ++nb);
    }
    phaseT(sm, i0, chatT, W1bp, hpartPriv, hid, wv, lane);
    gridbar(bar, ++nb);
    logitsPhase(sm, bid, hid, W2, b2, out, SLEN - 1);
}

// ---------------------------------------------------------------------------
extern "C" void kernel_launch(void* const* d_in, const int* in_sizes, int n_in,
                              void* d_out, int out_size, void* d_ws, size_t ws_size,
                              hipStream_t stream)
{
    const int*   y    = (const int*)  d_in[0];
    const float* enc  = (const float*)d_in[1];
    const float* emb  = (const float*)d_in[2];
    const float* aWih = (const float*)d_in[3];
    const float* aWhh = (const float*)d_in[4];
    const float* abih = (const float*)d_in[5];
    const float* abhh = (const float*)d_in[6];
    const float* rWih = (const float*)d_in[7];
    const float* rWhh = (const float*)d_in[8];
    const float* rbih = (const float*)d_in[9];
    const float* rbhh = (const float*)d_in[10];
    const float* Wsw  = (const float*)d_in[11];
    const float* Wsb  = (const float*)d_in[12];
    const float* Whw  = (const float*)d_in[13];
    const float* Whb  = (const float*)d_in[14];
    const float* W1   = (const float*)d_in[15];
    const float* b1   = (const float*)d_in[16];
    const float* W2   = (const float*)d_in[17];
    const float* b2   = (const float*)d_in[18];
    float* out = (float*)d_out;

    char* base = (char*)d_ws;
    unsigned* bar = (unsigned*)base;                 base += 4096;
    // zero region (f16 transposed state): h0(2), hs0(2), hs1(2), chat = 448KB
    __half* h0T   = (__half*)base;                   base += 2 * 65536;
    __half* hs0T  = (__half*)base;                   base += 2 * 65536;
    __half* hs1T  = (__half*)base;                   base += 2 * 65536;
    __half* chatT = (__half*)base;                   base += 65536;
    size_t zeroBytes = (size_t)(base - (char*)h0T);
    float* u      = (float*)base;                    base += 131072;
    float* hid    = (float*)base;                    base += 131072;
    float* pv     = (float*)base;                    base += 524288;
    float* pm     = (float*)base;                    base += 1024;
    float* ps     = (float*)base;                    base += 1024;
    float* Pm     = (float*)base;                    base += 1048576;
    float* p0v    = (float*)base;                    base += 2048;
    float* Wp     = (float*)base;                    base += (size_t)G4 * HID * 4;
    float* W1bp   = (float*)base;                    base += (size_t)HID * HID * 4;
    float* bihEff = (float*)base;                    base += 8192;
    float* b1eff  = (float*)base;                    base += 2048;
    __half* xemb16 = (__half*)base;                  base += (size_t)SLEN * BS * EMB * 2;
    __half* enc16  = (__half*)base;                  base += (size_t)BS * LLEN * HID * 2;
    size_t need = (size_t)(base - (char*)d_ws);
    if (ws_size < need) return;   // loud failure (output stays zero)

    hipMemsetAsync(bar, 0, 4096, stream);
    hipMemsetAsync(h0T, 0, zeroBytes, stream);

    k_embed16T<<<(SLEN * BS * EMB) / 256, 256, 0, stream>>>(y, emb, xemb16);
    k_cast<<<4096, 256, 0, stream>>>(enc, enc16, (BS * LLEN * HID) / 4);
    k_pmat<<<HID, 256, 0, stream>>>(Whw, Wsw, Wsb, Pm, p0v);
    k_fold<<<G4 + HID, 256, 0, stream>>>(aWih, W1, Whw, Whb, abih, b1,
                                         Wp, W1bp, bihEff, b1eff);

    k_seq<<<NB, NT, 0, stream>>>(xemb16, enc16,
        aWih, aWhh, bihEff, abhh, rWih, rWhh, rbih, rbhh,
        Pm, p0v, W1, b1eff, Wp, W1bp, W2, b2,
        h0T, hs0T, hs1T, chatT, u, hid, pv, pm, ps, out, bar);
}